// Round 10
// baseline (162.243 us; speedup 1.0000x reference)
//
#include <hip/hip_runtime.h>

#define SELU_S  1.0507009873554805f
#define SELU_SA (1.0507009873554805f * 1.6732632423543772f)

typedef __attribute__((ext_vector_type(8)))  short        bf16x8;
typedef __attribute__((ext_vector_type(16))) float        f32x16;
typedef __attribute__((ext_vector_type(2)))  float        f32x2;
typedef __attribute__((ext_vector_type(4)))  unsigned int u32x4;

#define MFMA(a,b,c) __builtin_amdgcn_mfma_f32_32x32x16_bf16((a),(b),(c),0,0,0)
#define BC(u) __builtin_bit_cast(bf16x8, (u))

// One-time prepped weight fragments (written by prep_kernel, read by cnf_kernel).
// NEW layout (frag = 256 u32 = 64 lanes x 16 B) — arranged so both hidden
// layers read h/m banks from LDS and l banks from GLOBAL (uniform address
// spaces per bank => the two layers can share ONE runtime-looped body,
// halving code size; theory: 30 KB straight-line body thrashes the 32 KB L1I):
//   0..3   L1 packed frags
//   4      quads: w1q[32] float4 | w4q[32] float4 (1 KB)
//   5..12  W2h | 13..20 W2m        <- LDS
//   21..28 W3h | 29..36 W3m        <- LDS
//   37..44 W2l | 45..52 W3l        <- GLOBAL-resident (8 reads/wave/layer)
//   53*256..+127 : b2[64] | b3[64] f32 bits (staged to LDS)
// LDS image = frags 0..36 + biases = 38400 B; 3 blocks x 40KB (8KB-granularity
// model from R7) = 120 KB <= 160 KB -> 3-block residency holds.
__device__ __align__(16) unsigned int g_frags[53*256 + 128];

// ---- one-time (preprocessing) software RNE ----
__device__ __forceinline__ unsigned int rne_bits(float f){
    unsigned int b = __float_as_uint(f);
    return b + 0x7fffu + ((b >> 16) & 1u);
}
__device__ __forceinline__ unsigned short lvl16(float v, int lvl){
    unsigned int r0 = rne_bits(v);
    if (lvl == 0) return (unsigned short)(r0 >> 16);
    float v1 = v - __uint_as_float(r0 & 0xffff0000u);
    unsigned int r1 = rne_bits(v1);
    if (lvl == 1) return (unsigned short)(r1 >> 16);
    float v2 = v1 - __uint_as_float(r1 & 0xffff0000u);
    return (unsigned short)(rne_bits(v2) >> 16);
}

// ---- hot-path split primitive ----
__device__ __forceinline__ unsigned int cvtpk(float a, float b){
    unsigned int r;
    asm("v_cvt_pk_bf16_f32 %0, %1, %2" : "=v"(r) : "v"(a), "v"(b));
    return r;
}
__device__ __forceinline__ f32x2 unpk2(unsigned int p){
    f32x2 r;
    r.x = __uint_as_float(p << 16);
    r.y = __uint_as_float(p & 0xffff0000u);
    return r;
}
__device__ __forceinline__ f32x2 mk2(float v){ return f32x2{v, v}; }

__device__ __forceinline__ void split2_v(f32x2 v, unsigned int& hi, unsigned int& lo){
    hi = cvtpk(v.x, v.y);
    f32x2 r1 = v - unpk2(hi);                  // exact
    lo = cvtpk(r1.x, r1.y);
}
__device__ __forceinline__ void split3_v(f32x2 v,
                                         unsigned int& hi, unsigned int& mi, unsigned int& lo){
    hi = cvtpk(v.x, v.y);
    f32x2 r1 = v - unpk2(hi);
    mi = cvtpk(r1.x, r1.y);
    f32x2 r2 = r1 - unpk2(mi);
    lo = cvtpk(r2.x, r2.y);                    // total residual <= 2^-24|v|
}
__device__ __forceinline__ void split3s(float a, float b,
                                        unsigned int& hi, unsigned int& mi, unsigned int& lo){
    split3_v(f32x2{a, b}, hi, mi, lo);
}

__device__ __forceinline__ f32x16 fzero(){
    f32x16 z;
    #pragma unroll
    for (int i = 0; i < 16; ++i) z[i] = 0.f;
    return z;
}

// works for both LDS-derived and global pointers (addrspace recovered after inlining)
__device__ __forceinline__ bf16x8 ldfrag(const unsigned int* src, int fid, int lane4){
    u32x4 u = *(const u32x4*)(src + fid*256 + lane4);
    return __builtin_bit_cast(bf16x8, u);
}

// SELU value+derivative for a packed pair
__device__ __forceinline__ void selu_pair(f32x2 z, f32x2& h, f32x2& d){
    f32x2 e{__expf(z.x), __expf(z.y)};
    f32x2 hn = e * mk2(SELU_SA) - mk2(SELU_SA);
    f32x2 hp = z * mk2(SELU_S);
    f32x2 dn = e * mk2(SELU_SA);
    h.x = z.x > 0.f ? hp.x : hn.x;
    h.y = z.y > 0.f ? hp.y : hn.y;
    d.x = z.x > 0.f ? SELU_S : dn.x;
    d.y = z.y > 0.f ? SELU_S : dn.y;
}

// C-layout (m74/m101): col = lane&31 = point, row = (r&3)+8*(r>>2)+4*(lane>>5), j = row+32t
// B in-lane bijection: per (kf,v,g):
//   j0 = 4g + (2v&3) + 8*(v>>1) + 16*(kf&1) + 32*(kf>>1), j1 = j0+1

// L1 epilogue (per t): z from Ch (b1 folded into MFMA); tangents = d * W1-cols.
__device__ __forceinline__ void epilogue_L1(int t, const float4* __restrict__ w1q, int g,
                                            f32x16& Ch,
                                            u32x4 (&Bh)[3][4], u32x4 (&Bm0)[4], u32x4 (&Bl)[3][4]){
    #pragma unroll
    for (int kfh = 0; kfh < 2; ++kfh){
        const int kf = 2*t + kfh;
        #pragma unroll
        for (int v = 0; v < 4; ++v){
            const int r  = 8*kfh + 2*v;
            const int qi = (kf*4 + v)*2 + g;
            f32x2 z{Ch[r], Ch[r+1]};
            f32x2 h, d;
            selu_pair(z, h, d);
            float4 w = w1q[qi];             // {W1[j0,0],W1[j1,0],W1[j0,1],W1[j1,1]}
            f32x2 a = d * f32x2{w.x, w.y};
            f32x2 c = d * f32x2{w.z, w.w};
            unsigned int hi, mi, lo;
            split3_v(h, hi, mi, lo);
            Bh[0][kf][v] = hi; Bm0[kf][v] = mi; Bl[0][kf][v] = lo;
            split2_v(a, hi, lo); Bh[1][kf][v] = hi; Bl[1][kf][v] = lo;
            split2_v(c, hi, lo); Bh[2][kf][v] = hi; Bl[2][kf][v] = lo;
        }
    }
}

// Hidden-layer epilogue: FINAL=false rebuilds the SINGLE B buffer in place;
// FINAL=true fuses the fp32 L4. Bit-identical math to R9.
template<bool FINAL>
__device__ __forceinline__ void hidden_epilogue(int g,
                                                const f32x16 (&Ch)[2], const f32x16 (&Cu0)[2],
                                                const f32x16 (&Cu1)[2],
                                                const float* blds,
                                                const float4* __restrict__ w4q,
                                                u32x4 (&Bh)[3][4], u32x4 (&Bm0)[4], u32x4 (&Bl)[3][4],
                                                f32x2& dx0a, f32x2& dx1a, f32x2& tra){
    #pragma unroll
    for (int kf = 0; kf < 4; ++kf){
        const int t = kf >> 1;
        #pragma unroll
        for (int v = 0; v < 4; ++v){
            const int r  = 8*(kf & 1) + 2*v;
            const int qi = (kf*4 + v)*2 + g;
            const int j0 = 4*g + ((2*v) & 3) + 8*(v >> 1) + 16*(kf & 1) + 32*(kf >> 1);
            float2 bb = *(const float2*)(blds + j0);    // LDS broadcast (2 addrs/wave)
            f32x2 z{Ch[t][r], Ch[t][r+1]};
            z = z + f32x2{bb.x, bb.y};
            f32x2 h, d;
            selu_pair(z, h, d);
            f32x2 a = d * f32x2{Cu0[t][r], Cu0[t][r+1]};
            f32x2 c = d * f32x2{Cu1[t][r], Cu1[t][r+1]};
            if (FINAL){
                float4 w = w4q[qi];         // {W4[0][j0],W4[0][j1],W4[1][j0],W4[1][j1]}
                f32x2 wxy{w.x, w.y}, wzw{w.z, w.w};
                dx0a = dx0a + wxy * h;
                dx1a = dx1a + wzw * h;
                tra  = tra  + wxy * a;
                tra  = tra  + wzw * c;
            } else {
                unsigned int hi, mi, lo;
                split3_v(h, hi, mi, lo);
                Bh[0][kf][v] = hi; Bm0[kf][v] = mi; Bl[0][kf][v] = lo;
                split2_v(a, hi, lo); Bh[1][kf][v] = hi; Bl[1][kf][v] = lo;
                split2_v(c, hi, lo); Bh[2][kf][v] = hi; Bl[2][kf][v] = lo;
            }
        }
    }
}

// ---------- one-time weight preprocessing (grid 22 x 64) ----------
__global__ void prep_kernel(const float* __restrict__ W1, const float* __restrict__ b1,
                            const float* __restrict__ W2, const float* __restrict__ W3,
                            const float* __restrict__ W4,
                            const float* __restrict__ b2, const float* __restrict__ b3)
{
    const int p  = blockIdx.x;
    const int ln = threadIdx.x;                 // 0..63
    const int g  = ln >> 5, l5 = ln & 31;
    if (p < 4){                                 // L1 packed frags
        const int t = p >> 1, var = p & 1;
        const int j = l5 + 32*t;
        const int lvl = (g == 0) ? 0 : (var == 0 ? 1 : 2);
        float vals[4] = { W1[j*3+0], W1[j*3+1], W1[j*3+2], b1[j] };
        unsigned int* ph = &g_frags[p*256 + ln*4];
        #pragma unroll
        for (int v = 0; v < 4; ++v){
            float a = (2*v   < 4) ? vals[2*v]   : 0.f;
            float b = (2*v+1 < 4) ? vals[2*v+1] : 0.f;
            unsigned int wa = (2*v   < 4) ? (unsigned int)lvl16(a, lvl) : 0u;
            unsigned int wb = (2*v+1 < 4) ? (unsigned int)lvl16(b, lvl) : 0u;
            ph[v] = wa | (wb << 16);
        }
    } else if (p < 20){                         // W2 / W3 triple-split frags
        const bool isW2 = (p < 12);
        const int q = p - (isW2 ? 4 : 12), t = q >> 2, kf = q & 3, m = l5 + 32*t;
        const float* __restrict__ Wg = isW2 ? W2 : W3;
        const int hb = isW2 ? 5  : 21;          // h bank (LDS image)
        const int mb = isW2 ? 13 : 29;          // m bank (LDS image)
        const int lb = isW2 ? 37 : 45;          // l bank (global-resident)
        unsigned int* ph = &g_frags[(hb + q)*256 + ln*4];
        unsigned int* pm = &g_frags[(mb + q)*256 + ln*4];
        unsigned int* pl = &g_frags[(lb + q)*256 + ln*4];
        #pragma unroll
        for (int v = 0; v < 4; ++v){
            int e0 = 2*v, e1 = 2*v + 1;
            int ja = 4*g + (e0&3) + 8*(e0>>2) + 16*(kf&1) + 32*(kf>>1);
            int jb = 4*g + (e1&3) + 8*(e1>>2) + 16*(kf&1) + 32*(kf>>1);
            float a = Wg[m*64 + ja], b = Wg[m*64 + jb];
            unsigned int ra = rne_bits(a), rb = rne_bits(b);
            ph[v] = (ra >> 16) | (rb & 0xffff0000u);
            float a1 = a - __uint_as_float(ra & 0xffff0000u);
            float b1v = b - __uint_as_float(rb & 0xffff0000u);
            unsigned int rma = rne_bits(a1), rmb = rne_bits(b1v);
            pm[v] = (rma >> 16) | (rmb & 0xffff0000u);
            float a2 = a1 - __uint_as_float(rma & 0xffff0000u);
            float b2v = b1v - __uint_as_float(rmb & 0xffff0000u);
            pl[v] = (rne_bits(a2) >> 16) | (rne_bits(b2v) & 0xffff0000u);
        }
    } else if (p == 20){                        // j-ordered fp32 quads -> frag 4
        if (ln < 32){
            const int qi = ln;                  // (kf*4+v)*2+g
            const int g2 = qi & 1, vv = (qi >> 1) & 3, kf = qi >> 3;
            const int j0 = 4*g2 + ((2*vv) & 3) + 8*(vv >> 1) + 16*(kf & 1) + 32*(kf >> 1);
            float4* w1q = (float4*)&g_frags[4*256];
            float4* w4q = w1q + 32;
            w1q[qi] = {W1[j0*3+0], W1[(j0+1)*3+0], W1[j0*3+1], W1[(j0+1)*3+1]};
            w4q[qi] = {W4[j0], W4[j0+1], W4[64+j0], W4[64+j0+1]};
        }
    } else {                                    // p == 21: bias tables (fp32 bits)
        g_frags[53*256      + ln] = __float_as_uint(b2[ln]);
        g_frags[53*256 + 64 + ln] = __float_as_uint(b3[ln]);
    }
}

// LDS image (37.5 KB): frags 0..36 (L1 + quads + W2h/m + W3h/m) + b2|b3
#define OFF_Q (4*256)
#define OFF_B (37*256)
// launch_bounds(256,3): path-split keeps peak liveness within the 512/3=170
// budget (R6/R9: 84 arch VGPR, 3 blocks/CU, no spill).
__global__ __launch_bounds__(256, 3) void cnf_kernel(
    const float* __restrict__ tp, const float* __restrict__ x,
    const float* __restrict__ b4, float* __restrict__ out)
{
    __shared__ unsigned int ldsA[37*256 + 128]; // 38400 B

    // ---------- stage prepped frags + biases: vectorized global->LDS copy ----------
    {
        const u32x4* __restrict__ src = (const u32x4*)g_frags;
        u32x4* dst = (u32x4*)ldsA;
        for (int i = threadIdx.x; i < 37*64; i += 256) dst[i] = src[i];
        if (threadIdx.x < 32){
            ((u32x4*)(ldsA + OFF_B))[threadIdx.x] =
                ((const u32x4*)(g_frags + 53*256))[threadIdx.x];
        }
    }
    __syncthreads();

    const float4* w1q = (const float4*)&ldsA[OFF_Q];
    const float4* w4q = w1q + 32;
    const float*  b2l = (const float*)(ldsA + OFF_B);
    const float*  b3l = b2l + 64;

    // ---------- main (one 32-point group per wave) ----------
    const int lane  = threadIdx.x & 63;
    const int g     = lane >> 5, l5 = lane & 31;
    const int lane4 = lane * 4;
    const int wid   = blockIdx.x * 4 + (threadIdx.x >> 6);

    const float ts  = tp[0];

    unsigned int tsh, tsm, tsl;
    split3s(ts, 1.0f, tsh, tsm, tsl);        // [ts, 1.0]; 1.0 exact

    const int n = wid*32 + l5;
    const float x0 = x[n*3 + 0], x1 = x[n*3 + 1];

    unsigned int xh, xm, xl;
    split3s(x0, x1, xh, xm, xl);
    const u32x4 Bp1 = { g ? xm : xh, g ? tsm : tsh, 0u, 0u };   // -> AhBh + AmBm
    const u32x4 Bp2 = { g ? xh : xm, g ? tsh : tsm, 0u, 0u };   // -> AhBm + AmBh
    const u32x4 Bp3 = { g ? xh : xl, g ? tsh : tsl, 0u, 0u };   // -> AhBl + AlBh

    u32x4 Bh[3][4], Bm0[4], Bl[3][4];       // SINGLE layer-interface buffer
    f32x2 dx0a = mk2(0.f), dx1a = mk2(0.f), tra = mk2(0.f);

    // ----- layer 1: z = W1ext @ [x0,x1,t,1] (6-term via 3 packed MFMAs) -----
    #pragma unroll
    for (int t = 0; t < 2; ++t){
        bf16x8 F1 = ldfrag(ldsA, 2*t,     lane4);   // [W1h | W1m]
        bf16x8 F3 = ldfrag(ldsA, 2*t + 1, lane4);   // [W1h | W1l]
        __builtin_amdgcn_s_setprio(1);
        f32x16 Ch = MFMA(F3, BC(Bp3), MFMA(F1, BC(Bp2), MFMA(F1, BC(Bp1), fzero())));
        __builtin_amdgcn_s_setprio(0);
        epilogue_L1(t, w1q, g, Ch, Bh, Bm0, Bl);
    }

    // ----- hidden layers: ONE runtime-looped body (code-size halving) -----
    // layer 0 = W2 (h/m LDS frags 5/13, l global 37), epilogue rebuilds B;
    // layer 1 = W3 (h/m LDS frags 21/29, l global 45), acc flows to final.
    // All register arrays statically indexed (rule #20); per-chain MFMA order
    // identical to R6/R9 -> bit-identical accumulation.
    f32x16 Ch[2], Cu0[2], Cu1[2];
    #pragma unroll 1
    for (int layer = 0; layer < 2; ++layer){
        const int fH = 5 + 16*layer;
        const int fM = fH + 8;
        const unsigned int* gl = g_frags + (37 + 8*layer)*256;   // l bank (global)

        // ---- phase-u0: tangent path 0, 4-term ----
        Cu0[0] = fzero(); Cu0[1] = fzero();
        __builtin_amdgcn_s_setprio(1);
        #pragma unroll
        for (int kf = 0; kf < 4; ++kf){
            #pragma unroll
            for (int t = 0; t < 2; ++t){
                const int q = t*4 + kf;
                bf16x8 ah = ldfrag(ldsA, fH + q, lane4);
                bf16x8 am = ldfrag(ldsA, fM + q, lane4);
                Cu0[t] = MFMA(am, BC(Bl[1][kf]),
                         MFMA(am, BC(Bh[1][kf]),
                         MFMA(ah, BC(Bl[1][kf]),
                         MFMA(ah, BC(Bh[1][kf]), Cu0[t]))));
            }
        }
        __builtin_amdgcn_sched_barrier(0);

        // ---- phase-u1: tangent path 1, 4-term ----
        Cu1[0] = fzero(); Cu1[1] = fzero();
        #pragma unroll
        for (int kf = 0; kf < 4; ++kf){
            #pragma unroll
            for (int t = 0; t < 2; ++t){
                const int q = t*4 + kf;
                bf16x8 ah = ldfrag(ldsA, fH + q, lane4);
                bf16x8 am = ldfrag(ldsA, fM + q, lane4);
                Cu1[t] = MFMA(am, BC(Bl[2][kf]),
                         MFMA(am, BC(Bh[2][kf]),
                         MFMA(ah, BC(Bl[2][kf]),
                         MFMA(ah, BC(Bh[2][kf]), Cu1[t]))));
            }
        }
        __builtin_amdgcn_sched_barrier(0);

        // ---- phase-h: z-path, 6-term (residual ~2^-24); l frags from global ----
        Ch[0] = fzero(); Ch[1] = fzero();
        #pragma unroll
        for (int kf = 0; kf < 4; ++kf){
            #pragma unroll
            for (int t = 0; t < 2; ++t){
                const int q = t*4 + kf;
                bf16x8 ah = ldfrag(ldsA, fH + q, lane4);
                bf16x8 am = ldfrag(ldsA, fM + q, lane4);
                bf16x8 al = ldfrag(gl,   q,      lane4);
                Ch[t] = MFMA(al, BC(Bh[0][kf]),
                        MFMA(am, BC(Bm0[kf]),
                        MFMA(ah, BC(Bl[0][kf]),
                        MFMA(am, BC(Bh[0][kf]),
                        MFMA(ah, BC(Bm0[kf]),
                        MFMA(ah, BC(Bh[0][kf]), Ch[t]))))));
            }
        }
        __builtin_amdgcn_s_setprio(0);
        __builtin_amdgcn_sched_barrier(0);

        // ---- layer-0 epilogue: rebuild B in place (uniform branch) ----
        if (layer == 0){
            hidden_epilogue<false>(g, Ch, Cu0, Cu1, b2l, nullptr,
                                   Bh, Bm0, Bl, dx0a, dx1a, tra);
        }
    }

    // ----- final epilogue: fp32 L4 fused (consumes layer-1 acc) -----
    hidden_epilogue<true>(g, Ch, Cu0, Cu1, b3l, w4q,
                          Bh, Bm0, Bl, dx0a, dx1a, tra);

    // ----- pair-reduce + cross-half reduce -----
    float dx0 = dx0a.x + dx0a.y;
    float dx1 = dx1a.x + dx1a.y;
    float tr  = tra.x  + tra.y;
    dx0 += __shfl_xor(dx0, 32, 64);
    dx1 += __shfl_xor(dx1, 32, 64);
    tr  += __shfl_xor(tr,  32, 64);
    if (g == 0){
        const float b40 = b4[0], b41 = b4[1];   // loaded late: keeps them out of
        out[n*3 + 0] = dx0 + b40;               // the whole-kernel live range
        out[n*3 + 1] = dx1 + b41;
        out[n*3 + 2] = tr;
    }
}

extern "C" void kernel_launch(void* const* d_in, const int* in_sizes, int n_in,
                              void* d_out, int out_size, void* d_ws, size_t ws_size,
                              hipStream_t stream) {
    const float* t  = (const float*)d_in[0];
    const float* x  = (const float*)d_in[1];
    const float* W1 = (const float*)d_in[2];
    const float* b1 = (const float*)d_in[3];
    const float* W2 = (const float*)d_in[4];
    const float* b2 = (const float*)d_in[5];
    const float* W3 = (const float*)d_in[6];
    const float* b3 = (const float*)d_in[7];
    const float* W4 = (const float*)d_in[8];
    const float* b4 = (const float*)d_in[9];
    float* out = (float*)d_out;

    prep_kernel<<<22, 64, 0, stream>>>(W1, b1, W2, W3, W4, b2, b3);
    cnf_kernel<<<2048, 256, 0, stream>>>(t, x, b4, out);
}

// Round 11
// 68.004 us; speedup vs baseline: 2.3858x; 2.3858x over previous
//
#include <hip/hip_runtime.h>

#define SELU_S  1.0507009873554805f
#define SELU_SA (1.0507009873554805f * 1.6732632423543772f)

typedef __attribute__((ext_vector_type(8)))  short        bf16x8;
typedef __attribute__((ext_vector_type(16))) float        f32x16;
typedef __attribute__((ext_vector_type(2)))  float        f32x2;
typedef __attribute__((ext_vector_type(4)))  unsigned int u32x4;

#define MFMA(a,b,c) __builtin_amdgcn_mfma_f32_32x32x16_bf16((a),(b),(c),0,0,0)
#define BC(u) __builtin_bit_cast(bf16x8, (u))

// One-time prepped weight fragments (written by prep_kernel, read by cnf_kernel).
// Layout (frag = 256 u32 = 64 lanes x 16 B):
//   0..3   L1 packed frags
//   4..27  W2 h(4..11) | m(12..19) | l(20..27)
//   28     quads: w1q[32] float4 | w4q[32] float4 (1 KB)
//   29..52 W3 h(29..36) | m(37..44) | l(45..52)   <- stays in GLOBAL
//   53*256 .. +127 : b2[64] | b3[64] as f32 bits  <- staged to LDS
// Session ledger (what is proven, rounds R1-R10):
//   R5/R6: path-split u0->u1->h + launch_bounds(256,3) => 84 VGPR, 3 blocks/CU
//          (occupancy 20%->28%, 82->75 us). The one real win.
//   R7:    staging W3 into LDS (54 KB) breaks 3-block residency => keep W3 global.
//   R3/R4: wave-stagger and MFMA-chain-ILP reorders: null.
//   R8:    2-groups-per-wave runtime loop: post-timing divergence (cross-call
//          scratch state). R10: shared-layer runtime loop: silent scratch spill
//          (FETCH 187 MB / WRITE 540 MB). The LOOP-FREE body is load-bearing.
//   R9:    bias-to-LDS: neutral; kept (marginally cleaner epilogue).
// This file is the verified R9 configuration: 75 us/dispatch, absmax 0.09375.
__device__ __align__(16) unsigned int g_frags[53*256 + 128];

// ---- one-time (preprocessing) software RNE ----
__device__ __forceinline__ unsigned int rne_bits(float f){
    unsigned int b = __float_as_uint(f);
    return b + 0x7fffu + ((b >> 16) & 1u);
}
__device__ __forceinline__ unsigned short lvl16(float v, int lvl){
    unsigned int r0 = rne_bits(v);
    if (lvl == 0) return (unsigned short)(r0 >> 16);
    float v1 = v - __uint_as_float(r0 & 0xffff0000u);
    unsigned int r1 = rne_bits(v1);
    if (lvl == 1) return (unsigned short)(r1 >> 16);
    float v2 = v1 - __uint_as_float(r1 & 0xffff0000u);
    return (unsigned short)(rne_bits(v2) >> 16);
}

// ---- hot-path split primitive ----
__device__ __forceinline__ unsigned int cvtpk(float a, float b){
    unsigned int r;
    asm("v_cvt_pk_bf16_f32 %0, %1, %2" : "=v"(r) : "v"(a), "v"(b));
    return r;
}
__device__ __forceinline__ f32x2 unpk2(unsigned int p){
    f32x2 r;
    r.x = __uint_as_float(p << 16);
    r.y = __uint_as_float(p & 0xffff0000u);
    return r;
}
__device__ __forceinline__ f32x2 mk2(float v){ return f32x2{v, v}; }

__device__ __forceinline__ void split2_v(f32x2 v, unsigned int& hi, unsigned int& lo){
    hi = cvtpk(v.x, v.y);
    f32x2 r1 = v - unpk2(hi);                  // exact
    lo = cvtpk(r1.x, r1.y);
}
__device__ __forceinline__ void split3_v(f32x2 v,
                                         unsigned int& hi, unsigned int& mi, unsigned int& lo){
    hi = cvtpk(v.x, v.y);
    f32x2 r1 = v - unpk2(hi);
    mi = cvtpk(r1.x, r1.y);
    f32x2 r2 = r1 - unpk2(mi);
    lo = cvtpk(r2.x, r2.y);                    // total residual <= 2^-24|v|
}
__device__ __forceinline__ void split3s(float a, float b,
                                        unsigned int& hi, unsigned int& mi, unsigned int& lo){
    split3_v(f32x2{a, b}, hi, mi, lo);
}

__device__ __forceinline__ f32x16 fzero(){
    f32x16 z;
    #pragma unroll
    for (int i = 0; i < 16; ++i) z[i] = 0.f;
    return z;
}

// works for both LDS-derived and global pointers (addrspace recovered after inlining)
__device__ __forceinline__ bf16x8 ldfrag(const unsigned int* src, int fid, int lane4){
    u32x4 u = *(const u32x4*)(src + fid*256 + lane4);
    return __builtin_bit_cast(bf16x8, u);
}

// SELU value+derivative for a packed pair
__device__ __forceinline__ void selu_pair(f32x2 z, f32x2& h, f32x2& d){
    f32x2 e{__expf(z.x), __expf(z.y)};
    f32x2 hn = e * mk2(SELU_SA) - mk2(SELU_SA);
    f32x2 hp = z * mk2(SELU_S);
    f32x2 dn = e * mk2(SELU_SA);
    h.x = z.x > 0.f ? hp.x : hn.x;
    h.y = z.y > 0.f ? hp.y : hn.y;
    d.x = z.x > 0.f ? SELU_S : dn.x;
    d.y = z.y > 0.f ? SELU_S : dn.y;
}

// C-layout (m74/m101): col = lane&31 = point, row = (r&3)+8*(r>>2)+4*(lane>>5), j = row+32t
// B in-lane bijection: per (kf,v,g):
//   j0 = 4g + (2v&3) + 8*(v>>1) + 16*(kf&1) + 32*(kf>>1), j1 = j0+1

// L1 epilogue (per t): z from Ch (b1 folded into MFMA); tangents = d * W1-cols.
__device__ __forceinline__ void epilogue_L1(int t, const float4* __restrict__ w1q, int g,
                                            f32x16& Ch,
                                            u32x4 (&Bh)[3][4], u32x4 (&Bm0)[4], u32x4 (&Bl)[3][4]){
    #pragma unroll
    for (int kfh = 0; kfh < 2; ++kfh){
        const int kf = 2*t + kfh;
        #pragma unroll
        for (int v = 0; v < 4; ++v){
            const int r  = 8*kfh + 2*v;
            const int qi = (kf*4 + v)*2 + g;
            f32x2 z{Ch[r], Ch[r+1]};
            f32x2 h, d;
            selu_pair(z, h, d);
            float4 w = w1q[qi];             // {W1[j0,0],W1[j1,0],W1[j0,1],W1[j1,1]}
            f32x2 a = d * f32x2{w.x, w.y};
            f32x2 c = d * f32x2{w.z, w.w};
            unsigned int hi, mi, lo;
            split3_v(h, hi, mi, lo);
            Bh[0][kf][v] = hi; Bm0[kf][v] = mi; Bl[0][kf][v] = lo;
            split2_v(a, hi, lo); Bh[1][kf][v] = hi; Bl[1][kf][v] = lo;
            split2_v(c, hi, lo); Bh[2][kf][v] = hi; Bl[2][kf][v] = lo;
        }
    }
}

// Hidden layer, PATH-SPLIT form, phase order u0 -> u1 -> h (liveness-minimal,
// proven R6: 84 arch VGPR, 3 blocks/CU). Per-chain MFMA order unchanged ->
// bit-identical accumulation. sched_barrier(0) fences stop cross-phase
// hoisting (the R2 liveness-inflation failure mode).
// blds points at the LDS-resident bias table (2-address broadcast read, free).
template<bool FINAL>
__device__ __forceinline__ void hidden_layer(const unsigned int* wsrc, int lane4, int g,
                                             int fWh, int fWm, int fWl,
                                             const float* blds,
                                             const float4* __restrict__ w4q,
                                             u32x4 (&Bh)[3][4], u32x4 (&Bm0)[4], u32x4 (&Bl)[3][4],
                                             f32x2& dx0a, f32x2& dx1a, f32x2& tra){
    f32x16 Ch[2], Cu0[2], Cu1[2];

    // ---- phase-u0: tangent path 0, 4-term ----
    Cu0[0] = fzero(); Cu0[1] = fzero();
    __builtin_amdgcn_s_setprio(1);
    #pragma unroll
    for (int kf = 0; kf < 4; ++kf){
        #pragma unroll
        for (int t = 0; t < 2; ++t){
            const int q = t*4 + kf;
            bf16x8 ah = ldfrag(wsrc, fWh + q, lane4);
            bf16x8 am = ldfrag(wsrc, fWm + q, lane4);
            Cu0[t] = MFMA(am, BC(Bl[1][kf]),
                     MFMA(am, BC(Bh[1][kf]),
                     MFMA(ah, BC(Bl[1][kf]),
                     MFMA(ah, BC(Bh[1][kf]), Cu0[t]))));
        }
    }
    __builtin_amdgcn_sched_barrier(0);

    // ---- phase-u1: tangent path 1, 4-term ----
    Cu1[0] = fzero(); Cu1[1] = fzero();
    #pragma unroll
    for (int kf = 0; kf < 4; ++kf){
        #pragma unroll
        for (int t = 0; t < 2; ++t){
            const int q = t*4 + kf;
            bf16x8 ah = ldfrag(wsrc, fWh + q, lane4);
            bf16x8 am = ldfrag(wsrc, fWm + q, lane4);
            Cu1[t] = MFMA(am, BC(Bl[2][kf]),
                     MFMA(am, BC(Bh[2][kf]),
                     MFMA(ah, BC(Bl[2][kf]),
                     MFMA(ah, BC(Bh[2][kf]), Cu1[t]))));
        }
    }
    __builtin_amdgcn_sched_barrier(0);

    // ---- phase-h: z-path, 6-term (residual ~2^-24) ----
    Ch[0] = fzero(); Ch[1] = fzero();
    #pragma unroll
    for (int kf = 0; kf < 4; ++kf){
        #pragma unroll
        for (int t = 0; t < 2; ++t){
            const int q = t*4 + kf;
            bf16x8 ah = ldfrag(wsrc, fWh + q, lane4);
            bf16x8 am = ldfrag(wsrc, fWm + q, lane4);
            bf16x8 al = ldfrag(wsrc, fWl + q, lane4);
            Ch[t] = MFMA(al, BC(Bh[0][kf]),
                    MFMA(am, BC(Bm0[kf]),
                    MFMA(ah, BC(Bl[0][kf]),
                    MFMA(am, BC(Bh[0][kf]),
                    MFMA(ah, BC(Bm0[kf]),
                    MFMA(ah, BC(Bh[0][kf]), Ch[t]))))));
        }
    }
    __builtin_amdgcn_s_setprio(0);
    __builtin_amdgcn_sched_barrier(0);

    // ---- epilogue (overwrites the SINGLE B buffer in place) ----
    #pragma unroll
    for (int kf = 0; kf < 4; ++kf){
        const int t = kf >> 1;
        #pragma unroll
        for (int v = 0; v < 4; ++v){
            const int r  = 8*(kf & 1) + 2*v;
            const int qi = (kf*4 + v)*2 + g;
            const int j0 = 4*g + ((2*v) & 3) + 8*(v >> 1) + 16*(kf & 1) + 32*(kf >> 1);
            float2 bb = *(const float2*)(blds + j0);    // LDS broadcast (2 addrs/wave)
            f32x2 z{Ch[t][r], Ch[t][r+1]};
            z = z + f32x2{bb.x, bb.y};
            f32x2 h, d;
            selu_pair(z, h, d);
            f32x2 a = d * f32x2{Cu0[t][r], Cu0[t][r+1]};
            f32x2 c = d * f32x2{Cu1[t][r], Cu1[t][r+1]};
            if (FINAL){
                float4 w = w4q[qi];         // {W4[0][j0],W4[0][j1],W4[1][j0],W4[1][j1]}
                f32x2 wxy{w.x, w.y}, wzw{w.z, w.w};
                dx0a = dx0a + wxy * h;
                dx1a = dx1a + wzw * h;
                tra  = tra  + wxy * a;
                tra  = tra  + wzw * c;
            } else {
                unsigned int hi, mi, lo;
                split3_v(h, hi, mi, lo);
                Bh[0][kf][v] = hi; Bm0[kf][v] = mi; Bl[0][kf][v] = lo;
                split2_v(a, hi, lo); Bh[1][kf][v] = hi; Bl[1][kf][v] = lo;
                split2_v(c, hi, lo); Bh[2][kf][v] = hi; Bl[2][kf][v] = lo;
            }
        }
    }
}

// ---------- one-time weight preprocessing (grid 22 x 64) ----------
__global__ void prep_kernel(const float* __restrict__ W1, const float* __restrict__ b1,
                            const float* __restrict__ W2, const float* __restrict__ W3,
                            const float* __restrict__ W4,
                            const float* __restrict__ b2, const float* __restrict__ b3)
{
    const int p  = blockIdx.x;
    const int ln = threadIdx.x;                 // 0..63
    const int g  = ln >> 5, l5 = ln & 31;
    if (p < 4){                                 // L1 packed frags
        const int t = p >> 1, var = p & 1;
        const int j = l5 + 32*t;
        const int lvl = (g == 0) ? 0 : (var == 0 ? 1 : 2);
        float vals[4] = { W1[j*3+0], W1[j*3+1], W1[j*3+2], b1[j] };
        unsigned int* ph = &g_frags[p*256 + ln*4];
        #pragma unroll
        for (int v = 0; v < 4; ++v){
            float a = (2*v   < 4) ? vals[2*v]   : 0.f;
            float b = (2*v+1 < 4) ? vals[2*v+1] : 0.f;
            unsigned int wa = (2*v   < 4) ? (unsigned int)lvl16(a, lvl) : 0u;
            unsigned int wb = (2*v+1 < 4) ? (unsigned int)lvl16(b, lvl) : 0u;
            ph[v] = wa | (wb << 16);
        }
    } else if (p < 20){                         // W2 / W3 triple-split frags
        const bool isW2 = (p < 12);
        const int q = p - (isW2 ? 4 : 12), t = q >> 2, kf = q & 3, m = l5 + 32*t;
        const float* __restrict__ Wg = isW2 ? W2 : W3;
        const int base = isW2 ? 4 : 29;
        unsigned int* ph = &g_frags[(base      + q)*256 + ln*4];
        unsigned int* pm = &g_frags[(base + 8  + q)*256 + ln*4];
        unsigned int* pl = &g_frags[(base + 16 + q)*256 + ln*4];
        #pragma unroll
        for (int v = 0; v < 4; ++v){
            int e0 = 2*v, e1 = 2*v + 1;
            int ja = 4*g + (e0&3) + 8*(e0>>2) + 16*(kf&1) + 32*(kf>>1);
            int jb = 4*g + (e1&3) + 8*(e1>>2) + 16*(kf&1) + 32*(kf>>1);
            float a = Wg[m*64 + ja], b = Wg[m*64 + jb];
            unsigned int ra = rne_bits(a), rb = rne_bits(b);
            ph[v] = (ra >> 16) | (rb & 0xffff0000u);
            float a1 = a - __uint_as_float(ra & 0xffff0000u);
            float b1v = b - __uint_as_float(rb & 0xffff0000u);
            unsigned int rma = rne_bits(a1), rmb = rne_bits(b1v);
            pm[v] = (rma >> 16) | (rmb & 0xffff0000u);
            float a2 = a1 - __uint_as_float(rma & 0xffff0000u);
            float b2v = b1v - __uint_as_float(rmb & 0xffff0000u);
            pl[v] = (rne_bits(a2) >> 16) | (rne_bits(b2v) & 0xffff0000u);
        }
    } else if (p == 20){                        // j-ordered fp32 quads
        if (ln < 32){
            const int qi = ln;                  // (kf*4+v)*2+g
            const int g2 = qi & 1, vv = (qi >> 1) & 3, kf = qi >> 3;
            const int j0 = 4*g2 + ((2*vv) & 3) + 8*(vv >> 1) + 16*(kf & 1) + 32*(kf >> 1);
            float4* w1q = (float4*)&g_frags[28*256];
            float4* w4q = w1q + 32;
            w1q[qi] = {W1[j0*3+0], W1[(j0+1)*3+0], W1[j0*3+1], W1[(j0+1)*3+1]};
            w4q[qi] = {W4[j0], W4[j0+1], W4[64+j0], W4[64+j0+1]};
        }
    } else {                                    // p == 21: bias tables (fp32 bits)
        g_frags[53*256      + ln] = __float_as_uint(b2[ln]);
        g_frags[53*256 + 64 + ln] = __float_as_uint(b3[ln]);
    }
}

// LDS image (29.5 KB): frags 0..27 (L1 + W2) + quads at frag 28 + b2|b3 (512 B)
#define OFF_Q (28*256)
#define OFF_B (29*256)
// launch_bounds(256,3): path-split keeps peak liveness within the 512/3=170
// budget (R6/R9: 84 arch VGPR, 3 blocks/CU, no spill).
__global__ __launch_bounds__(256, 3) void cnf_kernel(
    const float* __restrict__ tp, const float* __restrict__ x,
    const float* __restrict__ b4, float* __restrict__ out)
{
    __shared__ unsigned int ldsA[29*256 + 128]; // 30208 B

    // ---------- stage prepped frags + biases: vectorized global->LDS copy ----------
    {
        const u32x4* __restrict__ src = (const u32x4*)g_frags;
        u32x4* dst = (u32x4*)ldsA;
        for (int i = threadIdx.x; i < 29*64; i += 256) dst[i] = src[i];
        if (threadIdx.x < 32){
            ((u32x4*)(ldsA + OFF_B))[threadIdx.x] =
                ((const u32x4*)(g_frags + 53*256))[threadIdx.x];
        }
    }
    __syncthreads();

    const float4* w1q = (const float4*)&ldsA[OFF_Q];
    const float4* w4q = w1q + 32;
    const float*  b2l = (const float*)(ldsA + OFF_B);
    const float*  b3l = b2l + 64;
    const unsigned int* gW3 = g_frags + 29*256; // W3 bank stays in global (L1/L2-hot)

    // ---------- main (one 32-point group per wave; loop-free body, see ledger) ----------
    const int lane  = threadIdx.x & 63;
    const int g     = lane >> 5, l5 = lane & 31;
    const int lane4 = lane * 4;
    const int wid   = blockIdx.x * 4 + (threadIdx.x >> 6);

    const float ts  = tp[0];

    unsigned int tsh, tsm, tsl;
    split3s(ts, 1.0f, tsh, tsm, tsl);        // [ts, 1.0]; 1.0 exact

    const int n = wid*32 + l5;
    const float x0 = x[n*3 + 0], x1 = x[n*3 + 1];

    unsigned int xh, xm, xl;
    split3s(x0, x1, xh, xm, xl);
    const u32x4 Bp1 = { g ? xm : xh, g ? tsm : tsh, 0u, 0u };   // -> AhBh + AmBm
    const u32x4 Bp2 = { g ? xh : xm, g ? tsh : tsm, 0u, 0u };   // -> AhBm + AmBh
    const u32x4 Bp3 = { g ? xh : xl, g ? tsh : tsl, 0u, 0u };   // -> AhBl + AlBh

    u32x4 Bh[3][4], Bm0[4], Bl[3][4];       // SINGLE layer-interface buffer
    f32x2 dx0a = mk2(0.f), dx1a = mk2(0.f), tra = mk2(0.f);

    // ----- layer 1: z = W1ext @ [x0,x1,t,1] (6-term via 3 packed MFMAs) -----
    #pragma unroll
    for (int t = 0; t < 2; ++t){
        bf16x8 F1 = ldfrag(ldsA, 2*t,     lane4);   // [W1h | W1m]
        bf16x8 F3 = ldfrag(ldsA, 2*t + 1, lane4);   // [W1h | W1l]
        __builtin_amdgcn_s_setprio(1);
        f32x16 Ch = MFMA(F3, BC(Bp3), MFMA(F1, BC(Bp2), MFMA(F1, BC(Bp1), fzero())));
        __builtin_amdgcn_s_setprio(0);
        epilogue_L1(t, w1q, g, Ch, Bh, Bm0, Bl);
    }

    // ----- layer 2 (LDS frags) / layer 3 (global frags, fp32 L4 fused) -----
    hidden_layer<false>(ldsA, lane4, g, 4, 12, 20, b2l, nullptr, Bh, Bm0, Bl, dx0a, dx1a, tra);
    hidden_layer<true >(gW3,  lane4, g, 0,  8, 16, b3l, w4q,     Bh, Bm0, Bl, dx0a, dx1a, tra);

    // ----- pair-reduce + cross-half reduce -----
    float dx0 = dx0a.x + dx0a.y;
    float dx1 = dx1a.x + dx1a.y;
    float tr  = tra.x  + tra.y;
    dx0 += __shfl_xor(dx0, 32, 64);
    dx1 += __shfl_xor(dx1, 32, 64);
    tr  += __shfl_xor(tr,  32, 64);
    if (g == 0){
        const float b40 = b4[0], b41 = b4[1];   // loaded late: keeps them out of
        out[n*3 + 0] = dx0 + b40;               // the whole-kernel live range
        out[n*3 + 1] = dx1 + b41;
        out[n*3 + 2] = tr;
    }
}

extern "C" void kernel_launch(void* const* d_in, const int* in_sizes, int n_in,
                              void* d_out, int out_size, void* d_ws, size_t ws_size,
                              hipStream_t stream) {
    const float* t  = (const float*)d_in[0];
    const float* x  = (const float*)d_in[1];
    const float* W1 = (const float*)d_in[2];
    const float* b1 = (const float*)d_in[3];
    const float* W2 = (const float*)d_in[4];
    const float* b2 = (const float*)d_in[5];
    const float* W3 = (const float*)d_in[6];
    const float* b3 = (const float*)d_in[7];
    const float* W4 = (const float*)d_in[8];
    const float* b4 = (const float*)d_in[9];
    float* out = (float*)d_out;

    prep_kernel<<<22, 64, 0, stream>>>(W1, b1, W2, W3, W4, b2, b3);
    cnf_kernel<<<2048, 256, 0, stream>>>(t, x, b4, out);
}

// Round 12
// 63.363 us; speedup vs baseline: 2.5605x; 1.0732x over previous
//
#include <hip/hip_runtime.h>

#define SELU_S  1.0507009873554805f
#define SELU_SA (1.0507009873554805f * 1.6732632423543772f)

typedef __attribute__((ext_vector_type(8)))  short        bf16x8;
typedef __attribute__((ext_vector_type(16))) float        f32x16;
typedef __attribute__((ext_vector_type(2)))  float        f32x2;
typedef __attribute__((ext_vector_type(4)))  unsigned int u32x4;

#define MFMA(a,b,c) __builtin_amdgcn_mfma_f32_32x32x16_bf16((a),(b),(c),0,0,0)
#define BC(u) __builtin_bit_cast(bf16x8, (u))

// One-time prepped weight fragments (written by prep_kernel, read by cnf_kernel).
// Layout (frag = 256 u32 = 64 lanes x 16 B):
//   0..3   L1 packed frags
//   4..27  W2 h(4..11) | m(12..19) | l(20..27)
//   28     quads: w1q[32] float4 | w4q[32] float4 (1 KB)
//   29..52 W3 h(29..36) | m(37..44) | l(45..52)   <- stays in GLOBAL
//   53*256 .. +127 : b2[64] | b3[64] as f32 bits  <- staged to LDS
// Session ledger (proven, R1-R11):
//   R5/R6: path-split u0->u1->h + launch_bounds(256,3) => 84 VGPR, 3 blocks/CU.
//   R7:    W3-in-LDS breaks 3-block residency => keep W3 global.
//   R3/R4: wave-stagger / MFMA-chain reorders: null.
//   R8/R10: runtime loops => scratch corruption/spill. LOOP-FREE body is law.
//   R9/R11: verified best 74.5 us/dispatch, 68.0 us bench, absmax 0.09375.
//   R12 (this): drop the am*Bl tangent term (~2^-18 relative) => 230->198 MFMA,
//   u-phase chains 4->3 deep. Registers/structure untouched.
__device__ __align__(16) unsigned int g_frags[53*256 + 128];

// ---- one-time (preprocessing) software RNE ----
__device__ __forceinline__ unsigned int rne_bits(float f){
    unsigned int b = __float_as_uint(f);
    return b + 0x7fffu + ((b >> 16) & 1u);
}
__device__ __forceinline__ unsigned short lvl16(float v, int lvl){
    unsigned int r0 = rne_bits(v);
    if (lvl == 0) return (unsigned short)(r0 >> 16);
    float v1 = v - __uint_as_float(r0 & 0xffff0000u);
    unsigned int r1 = rne_bits(v1);
    if (lvl == 1) return (unsigned short)(r1 >> 16);
    float v2 = v1 - __uint_as_float(r1 & 0xffff0000u);
    return (unsigned short)(rne_bits(v2) >> 16);
}

// ---- hot-path split primitive ----
__device__ __forceinline__ unsigned int cvtpk(float a, float b){
    unsigned int r;
    asm("v_cvt_pk_bf16_f32 %0, %1, %2" : "=v"(r) : "v"(a), "v"(b));
    return r;
}
__device__ __forceinline__ f32x2 unpk2(unsigned int p){
    f32x2 r;
    r.x = __uint_as_float(p << 16);
    r.y = __uint_as_float(p & 0xffff0000u);
    return r;
}
__device__ __forceinline__ f32x2 mk2(float v){ return f32x2{v, v}; }

__device__ __forceinline__ void split2_v(f32x2 v, unsigned int& hi, unsigned int& lo){
    hi = cvtpk(v.x, v.y);
    f32x2 r1 = v - unpk2(hi);                  // exact
    lo = cvtpk(r1.x, r1.y);
}
__device__ __forceinline__ void split3_v(f32x2 v,
                                         unsigned int& hi, unsigned int& mi, unsigned int& lo){
    hi = cvtpk(v.x, v.y);
    f32x2 r1 = v - unpk2(hi);
    mi = cvtpk(r1.x, r1.y);
    f32x2 r2 = r1 - unpk2(mi);
    lo = cvtpk(r2.x, r2.y);                    // total residual <= 2^-24|v|
}
__device__ __forceinline__ void split3s(float a, float b,
                                        unsigned int& hi, unsigned int& mi, unsigned int& lo){
    split3_v(f32x2{a, b}, hi, mi, lo);
}

__device__ __forceinline__ f32x16 fzero(){
    f32x16 z;
    #pragma unroll
    for (int i = 0; i < 16; ++i) z[i] = 0.f;
    return z;
}

// works for both LDS-derived and global pointers (addrspace recovered after inlining)
__device__ __forceinline__ bf16x8 ldfrag(const unsigned int* src, int fid, int lane4){
    u32x4 u = *(const u32x4*)(src + fid*256 + lane4);
    return __builtin_bit_cast(bf16x8, u);
}

// SELU value+derivative for a packed pair
__device__ __forceinline__ void selu_pair(f32x2 z, f32x2& h, f32x2& d){
    f32x2 e{__expf(z.x), __expf(z.y)};
    f32x2 hn = e * mk2(SELU_SA) - mk2(SELU_SA);
    f32x2 hp = z * mk2(SELU_S);
    f32x2 dn = e * mk2(SELU_SA);
    h.x = z.x > 0.f ? hp.x : hn.x;
    h.y = z.y > 0.f ? hp.y : hn.y;
    d.x = z.x > 0.f ? SELU_S : dn.x;
    d.y = z.y > 0.f ? SELU_S : dn.y;
}

// C-layout (m74/m101): col = lane&31 = point, row = (r&3)+8*(r>>2)+4*(lane>>5), j = row+32t
// B in-lane bijection: per (kf,v,g):
//   j0 = 4g + (2v&3) + 8*(v>>1) + 16*(kf&1) + 32*(kf>>1), j1 = j0+1

// L1 epilogue (per t): z from Ch (b1 folded into MFMA); tangents = d * W1-cols.
__device__ __forceinline__ void epilogue_L1(int t, const float4* __restrict__ w1q, int g,
                                            f32x16& Ch,
                                            u32x4 (&Bh)[3][4], u32x4 (&Bm0)[4], u32x4 (&Bl)[3][4]){
    #pragma unroll
    for (int kfh = 0; kfh < 2; ++kfh){
        const int kf = 2*t + kfh;
        #pragma unroll
        for (int v = 0; v < 4; ++v){
            const int r  = 8*kfh + 2*v;
            const int qi = (kf*4 + v)*2 + g;
            f32x2 z{Ch[r], Ch[r+1]};
            f32x2 h, d;
            selu_pair(z, h, d);
            float4 w = w1q[qi];             // {W1[j0,0],W1[j1,0],W1[j0,1],W1[j1,1]}
            f32x2 a = d * f32x2{w.x, w.y};
            f32x2 c = d * f32x2{w.z, w.w};
            unsigned int hi, mi, lo;
            split3_v(h, hi, mi, lo);
            Bh[0][kf][v] = hi; Bm0[kf][v] = mi; Bl[0][kf][v] = lo;
            split2_v(a, hi, lo); Bh[1][kf][v] = hi; Bl[1][kf][v] = lo;
            split2_v(c, hi, lo); Bh[2][kf][v] = hi; Bl[2][kf][v] = lo;
        }
    }
}

// Hidden layer, PATH-SPLIT form, phase order u0 -> u1 -> h (liveness-minimal,
// proven R6: 84 arch VGPR, 3 blocks/CU). sched_barrier(0) fences stop
// cross-phase hoisting (the R2 liveness-inflation failure mode).
// R12: tangent chains are 3-term (ah*Bh + ah*Bl + am*Bh); the dropped am*Bl
// term contributes ~2^-18 relative — below the chain's accepted residual.
// blds points at the LDS-resident bias table (2-address broadcast read, free).
template<bool FINAL>
__device__ __forceinline__ void hidden_layer(const unsigned int* wsrc, int lane4, int g,
                                             int fWh, int fWm, int fWl,
                                             const float* blds,
                                             const float4* __restrict__ w4q,
                                             u32x4 (&Bh)[3][4], u32x4 (&Bm0)[4], u32x4 (&Bl)[3][4],
                                             f32x2& dx0a, f32x2& dx1a, f32x2& tra){
    f32x16 Ch[2], Cu0[2], Cu1[2];

    // ---- phase-u0: tangent path 0, 3-term ----
    Cu0[0] = fzero(); Cu0[1] = fzero();
    __builtin_amdgcn_s_setprio(1);
    #pragma unroll
    for (int kf = 0; kf < 4; ++kf){
        #pragma unroll
        for (int t = 0; t < 2; ++t){
            const int q = t*4 + kf;
            bf16x8 ah = ldfrag(wsrc, fWh + q, lane4);
            bf16x8 am = ldfrag(wsrc, fWm + q, lane4);
            Cu0[t] = MFMA(am, BC(Bh[1][kf]),
                     MFMA(ah, BC(Bl[1][kf]),
                     MFMA(ah, BC(Bh[1][kf]), Cu0[t])));
        }
    }
    __builtin_amdgcn_sched_barrier(0);

    // ---- phase-u1: tangent path 1, 3-term ----
    Cu1[0] = fzero(); Cu1[1] = fzero();
    #pragma unroll
    for (int kf = 0; kf < 4; ++kf){
        #pragma unroll
        for (int t = 0; t < 2; ++t){
            const int q = t*4 + kf;
            bf16x8 ah = ldfrag(wsrc, fWh + q, lane4);
            bf16x8 am = ldfrag(wsrc, fWm + q, lane4);
            Cu1[t] = MFMA(am, BC(Bh[2][kf]),
                     MFMA(ah, BC(Bl[2][kf]),
                     MFMA(ah, BC(Bh[2][kf]), Cu1[t])));
        }
    }
    __builtin_amdgcn_sched_barrier(0);

    // ---- phase-h: z-path, 6-term (residual ~2^-24, unchanged) ----
    Ch[0] = fzero(); Ch[1] = fzero();
    #pragma unroll
    for (int kf = 0; kf < 4; ++kf){
        #pragma unroll
        for (int t = 0; t < 2; ++t){
            const int q = t*4 + kf;
            bf16x8 ah = ldfrag(wsrc, fWh + q, lane4);
            bf16x8 am = ldfrag(wsrc, fWm + q, lane4);
            bf16x8 al = ldfrag(wsrc, fWl + q, lane4);
            Ch[t] = MFMA(al, BC(Bh[0][kf]),
                    MFMA(am, BC(Bm0[kf]),
                    MFMA(ah, BC(Bl[0][kf]),
                    MFMA(am, BC(Bh[0][kf]),
                    MFMA(ah, BC(Bm0[kf]),
                    MFMA(ah, BC(Bh[0][kf]), Ch[t]))))));
        }
    }
    __builtin_amdgcn_s_setprio(0);
    __builtin_amdgcn_sched_barrier(0);

    // ---- epilogue (overwrites the SINGLE B buffer in place) ----
    #pragma unroll
    for (int kf = 0; kf < 4; ++kf){
        const int t = kf >> 1;
        #pragma unroll
        for (int v = 0; v < 4; ++v){
            const int r  = 8*(kf & 1) + 2*v;
            const int qi = (kf*4 + v)*2 + g;
            const int j0 = 4*g + ((2*v) & 3) + 8*(v >> 1) + 16*(kf & 1) + 32*(kf >> 1);
            float2 bb = *(const float2*)(blds + j0);    // LDS broadcast (2 addrs/wave)
            f32x2 z{Ch[t][r], Ch[t][r+1]};
            z = z + f32x2{bb.x, bb.y};
            f32x2 h, d;
            selu_pair(z, h, d);
            f32x2 a = d * f32x2{Cu0[t][r], Cu0[t][r+1]};
            f32x2 c = d * f32x2{Cu1[t][r], Cu1[t][r+1]};
            if (FINAL){
                float4 w = w4q[qi];         // {W4[0][j0],W4[0][j1],W4[1][j0],W4[1][j1]}
                f32x2 wxy{w.x, w.y}, wzw{w.z, w.w};
                dx0a = dx0a + wxy * h;
                dx1a = dx1a + wzw * h;
                tra  = tra  + wxy * a;
                tra  = tra  + wzw * c;
            } else {
                unsigned int hi, mi, lo;
                split3_v(h, hi, mi, lo);
                Bh[0][kf][v] = hi; Bm0[kf][v] = mi; Bl[0][kf][v] = lo;
                split2_v(a, hi, lo); Bh[1][kf][v] = hi; Bl[1][kf][v] = lo;
                split2_v(c, hi, lo); Bh[2][kf][v] = hi; Bl[2][kf][v] = lo;
            }
        }
    }
}

// ---------- one-time weight preprocessing (grid 22 x 64) ----------
__global__ void prep_kernel(const float* __restrict__ W1, const float* __restrict__ b1,
                            const float* __restrict__ W2, const float* __restrict__ W3,
                            const float* __restrict__ W4,
                            const float* __restrict__ b2, const float* __restrict__ b3)
{
    const int p  = blockIdx.x;
    const int ln = threadIdx.x;                 // 0..63
    const int g  = ln >> 5, l5 = ln & 31;
    if (p < 4){                                 // L1 packed frags
        const int t = p >> 1, var = p & 1;
        const int j = l5 + 32*t;
        const int lvl = (g == 0) ? 0 : (var == 0 ? 1 : 2);
        float vals[4] = { W1[j*3+0], W1[j*3+1], W1[j*3+2], b1[j] };
        unsigned int* ph = &g_frags[p*256 + ln*4];
        #pragma unroll
        for (int v = 0; v < 4; ++v){
            float a = (2*v   < 4) ? vals[2*v]   : 0.f;
            float b = (2*v+1 < 4) ? vals[2*v+1] : 0.f;
            unsigned int wa = (2*v   < 4) ? (unsigned int)lvl16(a, lvl) : 0u;
            unsigned int wb = (2*v+1 < 4) ? (unsigned int)lvl16(b, lvl) : 0u;
            ph[v] = wa | (wb << 16);
        }
    } else if (p < 20){                         // W2 / W3 triple-split frags
        const bool isW2 = (p < 12);
        const int q = p - (isW2 ? 4 : 12), t = q >> 2, kf = q & 3, m = l5 + 32*t;
        const float* __restrict__ Wg = isW2 ? W2 : W3;
        const int base = isW2 ? 4 : 29;
        unsigned int* ph = &g_frags[(base      + q)*256 + ln*4];
        unsigned int* pm = &g_frags[(base + 8  + q)*256 + ln*4];
        unsigned int* pl = &g_frags[(base + 16 + q)*256 + ln*4];
        #pragma unroll
        for (int v = 0; v < 4; ++v){
            int e0 = 2*v, e1 = 2*v + 1;
            int ja = 4*g + (e0&3) + 8*(e0>>2) + 16*(kf&1) + 32*(kf>>1);
            int jb = 4*g + (e1&3) + 8*(e1>>2) + 16*(kf&1) + 32*(kf>>1);
            float a = Wg[m*64 + ja], b = Wg[m*64 + jb];
            unsigned int ra = rne_bits(a), rb = rne_bits(b);
            ph[v] = (ra >> 16) | (rb & 0xffff0000u);
            float a1 = a - __uint_as_float(ra & 0xffff0000u);
            float b1v = b - __uint_as_float(rb & 0xffff0000u);
            unsigned int rma = rne_bits(a1), rmb = rne_bits(b1v);
            pm[v] = (rma >> 16) | (rmb & 0xffff0000u);
            float a2 = a1 - __uint_as_float(rma & 0xffff0000u);
            float b2v = b1v - __uint_as_float(rmb & 0xffff0000u);
            pl[v] = (rne_bits(a2) >> 16) | (rne_bits(b2v) & 0xffff0000u);
        }
    } else if (p == 20){                        // j-ordered fp32 quads
        if (ln < 32){
            const int qi = ln;                  // (kf*4+v)*2+g
            const int g2 = qi & 1, vv = (qi >> 1) & 3, kf = qi >> 3;
            const int j0 = 4*g2 + ((2*vv) & 3) + 8*(vv >> 1) + 16*(kf & 1) + 32*(kf >> 1);
            float4* w1q = (float4*)&g_frags[28*256];
            float4* w4q = w1q + 32;
            w1q[qi] = {W1[j0*3+0], W1[(j0+1)*3+0], W1[j0*3+1], W1[(j0+1)*3+1]};
            w4q[qi] = {W4[j0], W4[j0+1], W4[64+j0], W4[64+j0+1]};
        }
    } else {                                    // p == 21: bias tables (fp32 bits)
        g_frags[53*256      + ln] = __float_as_uint(b2[ln]);
        g_frags[53*256 + 64 + ln] = __float_as_uint(b3[ln]);
    }
}

// LDS image (29.5 KB): frags 0..27 (L1 + W2) + quads at frag 28 + b2|b3 (512 B)
#define OFF_Q (28*256)
#define OFF_B (29*256)
// launch_bounds(256,3): path-split keeps peak liveness within the 512/3=170
// budget (R6/R9/R11: 84 arch VGPR, 3 blocks/CU, no spill).
__global__ __launch_bounds__(256, 3) void cnf_kernel(
    const float* __restrict__ tp, const float* __restrict__ x,
    const float* __restrict__ b4, float* __restrict__ out)
{
    __shared__ unsigned int ldsA[29*256 + 128]; // 30208 B

    // ---------- stage prepped frags + biases: vectorized global->LDS copy ----------
    {
        const u32x4* __restrict__ src = (const u32x4*)g_frags;
        u32x4* dst = (u32x4*)ldsA;
        for (int i = threadIdx.x; i < 29*64; i += 256) dst[i] = src[i];
        if (threadIdx.x < 32){
            ((u32x4*)(ldsA + OFF_B))[threadIdx.x] =
                ((const u32x4*)(g_frags + 53*256))[threadIdx.x];
        }
    }
    __syncthreads();

    const float4* w1q = (const float4*)&ldsA[OFF_Q];
    const float4* w4q = w1q + 32;
    const float*  b2l = (const float*)(ldsA + OFF_B);
    const float*  b3l = b2l + 64;
    const unsigned int* gW3 = g_frags + 29*256; // W3 bank stays in global (L1/L2-hot)

    // ---------- main (one 32-point group per wave; loop-free body, see ledger) ----------
    const int lane  = threadIdx.x & 63;
    const int g     = lane >> 5, l5 = lane & 31;
    const int lane4 = lane * 4;
    const int wid   = blockIdx.x * 4 + (threadIdx.x >> 6);

    const float ts  = tp[0];

    unsigned int tsh, tsm, tsl;
    split3s(ts, 1.0f, tsh, tsm, tsl);        // [ts, 1.0]; 1.0 exact

    const int n = wid*32 + l5;
    const float x0 = x[n*3 + 0], x1 = x[n*3 + 1];

    unsigned int xh, xm, xl;
    split3s(x0, x1, xh, xm, xl);
    const u32x4 Bp1 = { g ? xm : xh, g ? tsm : tsh, 0u, 0u };   // -> AhBh + AmBm
    const u32x4 Bp2 = { g ? xh : xm, g ? tsh : tsm, 0u, 0u };   // -> AhBm + AmBh
    const u32x4 Bp3 = { g ? xh : xl, g ? tsh : tsl, 0u, 0u };   // -> AhBl + AlBh

    u32x4 Bh[3][4], Bm0[4], Bl[3][4];       // SINGLE layer-interface buffer
    f32x2 dx0a = mk2(0.f), dx1a = mk2(0.f), tra = mk2(0.f);

    // ----- layer 1: z = W1ext @ [x0,x1,t,1] (6-term via 3 packed MFMAs) -----
    #pragma unroll
    for (int t = 0; t < 2; ++t){
        bf16x8 F1 = ldfrag(ldsA, 2*t,     lane4);   // [W1h | W1m]
        bf16x8 F3 = ldfrag(ldsA, 2*t + 1, lane4);   // [W1h | W1l]
        __builtin_amdgcn_s_setprio(1);
        f32x16 Ch = MFMA(F3, BC(Bp3), MFMA(F1, BC(Bp2), MFMA(F1, BC(Bp1), fzero())));
        __builtin_amdgcn_s_setprio(0);
        epilogue_L1(t, w1q, g, Ch, Bh, Bm0, Bl);
    }

    // ----- layer 2 (LDS frags) / layer 3 (global frags, fp32 L4 fused) -----
    hidden_layer<false>(ldsA, lane4, g, 4, 12, 20, b2l, nullptr, Bh, Bm0, Bl, dx0a, dx1a, tra);
    hidden_layer<true >(gW3,  lane4, g, 0,  8, 16, b3l, w4q,     Bh, Bm0, Bl, dx0a, dx1a, tra);

    // ----- pair-reduce + cross-half reduce -----
    float dx0 = dx0a.x + dx0a.y;
    float dx1 = dx1a.x + dx1a.y;
    float tr  = tra.x  + tra.y;
    dx0 += __shfl_xor(dx0, 32, 64);
    dx1 += __shfl_xor(dx1, 32, 64);
    tr  += __shfl_xor(tr,  32, 64);
    if (g == 0){
        const float b40 = b4[0], b41 = b4[1];   // loaded late: keeps them out of
        out[n*3 + 0] = dx0 + b40;               // the whole-kernel live range
        out[n*3 + 1] = dx1 + b41;
        out[n*3 + 2] = tr;
    }
}

extern "C" void kernel_launch(void* const* d_in, const int* in_sizes, int n_in,
                              void* d_out, int out_size, void* d_ws, size_t ws_size,
                              hipStream_t stream) {
    const float* t  = (const float*)d_in[0];
    const float* x  = (const float*)d_in[1];
    const float* W1 = (const float*)d_in[2];
    const float* b1 = (const float*)d_in[3];
    const float* W2 = (const float*)d_in[4];
    const float* b2 = (const float*)d_in[5];
    const float* W3 = (const float*)d_in[6];
    const float* b3 = (const float*)d_in[7];
    const float* W4 = (const float*)d_in[8];
    const float* b4 = (const float*)d_in[9];
    float* out = (float*)d_out;

    prep_kernel<<<22, 64, 0, stream>>>(W1, b1, W2, W3, W4, b2, b3);
    cnf_kernel<<<2048, 256, 0, stream>>>(t, x, b4, out);
}

// Round 13
// 56.462 us; speedup vs baseline: 2.8735x; 1.1222x over previous
//
#include <hip/hip_runtime.h>

#define SELU_S  1.0507009873554805f
#define SELU_SA (1.0507009873554805f * 1.6732632423543772f)

typedef __attribute__((ext_vector_type(8)))  short        bf16x8;
typedef __attribute__((ext_vector_type(16))) float        f32x16;
typedef __attribute__((ext_vector_type(2)))  float        f32x2;
typedef __attribute__((ext_vector_type(4)))  unsigned int u32x4;

#define MFMA(a,b,c) __builtin_amdgcn_mfma_f32_32x32x16_bf16((a),(b),(c),0,0,0)
#define BC(u) __builtin_bit_cast(bf16x8, (u))

// One-time prepped weight fragments (written by prep_kernel, read by cnf_kernel).
// Layout (frag = 256 u32 = 64 lanes x 16 B):
//   0..3   L1 packed frags
//   4..27  W2 h(4..11) | m(12..19) | l(20..27)
//   28     quads: w1q[32] float4 | w4q[32] float4 (1 KB)
//   29..52 W3 h(29..36) | m(37..44) | l(45..52)   <- stays in GLOBAL
//   53*256 .. +127 : b2[64] | b3[64] as f32 bits  <- staged to LDS
// Session ledger (proven, R1-R12):
//   R5/R6: path-split u0->u1->h + launch_bounds(256,3) => 84 VGPR, 3 blocks/CU.
//   R7:    W3-in-LDS breaks 3-block residency => keep W3 global.
//   R3/R4: wave-stagger / MFMA-chain reorders: null.
//   R8/R10: runtime loops => scratch corruption/spill. LOOP-FREE body is law.
//   R12:   drop am*Bl tangent term (230->198 MFMA): -5.4%, absmax UNCHANGED
//          0.09375 => max-error point is tangent-precision-insensitive.
//   R13 (this): drop ah*Bl tangent term too => 2-term tangent chains
//          (bf16-level tangent activations, 2-level weights): 198->166 MFMA,
//          Bl[1]/Bl[2] eliminated (split2_v -> cvtpk in epilogues, B 112->80).
//          z-path stays full 6-term (sign-flip/derivative-discontinuity safety).
__device__ __align__(16) unsigned int g_frags[53*256 + 128];

// ---- one-time (preprocessing) software RNE ----
__device__ __forceinline__ unsigned int rne_bits(float f){
    unsigned int b = __float_as_uint(f);
    return b + 0x7fffu + ((b >> 16) & 1u);
}
__device__ __forceinline__ unsigned short lvl16(float v, int lvl){
    unsigned int r0 = rne_bits(v);
    if (lvl == 0) return (unsigned short)(r0 >> 16);
    float v1 = v - __uint_as_float(r0 & 0xffff0000u);
    unsigned int r1 = rne_bits(v1);
    if (lvl == 1) return (unsigned short)(r1 >> 16);
    float v2 = v1 - __uint_as_float(r1 & 0xffff0000u);
    return (unsigned short)(rne_bits(v2) >> 16);
}

// ---- hot-path split primitive ----
__device__ __forceinline__ unsigned int cvtpk(float a, float b){
    unsigned int r;
    asm("v_cvt_pk_bf16_f32 %0, %1, %2" : "=v"(r) : "v"(a), "v"(b));
    return r;
}
__device__ __forceinline__ f32x2 unpk2(unsigned int p){
    f32x2 r;
    r.x = __uint_as_float(p << 16);
    r.y = __uint_as_float(p & 0xffff0000u);
    return r;
}
__device__ __forceinline__ f32x2 mk2(float v){ return f32x2{v, v}; }

__device__ __forceinline__ void split3_v(f32x2 v,
                                         unsigned int& hi, unsigned int& mi, unsigned int& lo){
    hi = cvtpk(v.x, v.y);
    f32x2 r1 = v - unpk2(hi);
    mi = cvtpk(r1.x, r1.y);
    f32x2 r2 = r1 - unpk2(mi);
    lo = cvtpk(r2.x, r2.y);                    // total residual <= 2^-24|v|
}
__device__ __forceinline__ void split3s(float a, float b,
                                        unsigned int& hi, unsigned int& mi, unsigned int& lo){
    split3_v(f32x2{a, b}, hi, mi, lo);
}

__device__ __forceinline__ f32x16 fzero(){
    f32x16 z;
    #pragma unroll
    for (int i = 0; i < 16; ++i) z[i] = 0.f;
    return z;
}

// works for both LDS-derived and global pointers (addrspace recovered after inlining)
__device__ __forceinline__ bf16x8 ldfrag(const unsigned int* src, int fid, int lane4){
    u32x4 u = *(const u32x4*)(src + fid*256 + lane4);
    return __builtin_bit_cast(bf16x8, u);
}

// SELU value+derivative for a packed pair
__device__ __forceinline__ void selu_pair(f32x2 z, f32x2& h, f32x2& d){
    f32x2 e{__expf(z.x), __expf(z.y)};
    f32x2 hn = e * mk2(SELU_SA) - mk2(SELU_SA);
    f32x2 hp = z * mk2(SELU_S);
    f32x2 dn = e * mk2(SELU_SA);
    h.x = z.x > 0.f ? hp.x : hn.x;
    h.y = z.y > 0.f ? hp.y : hn.y;
    d.x = z.x > 0.f ? SELU_S : dn.x;
    d.y = z.y > 0.f ? SELU_S : dn.y;
}

// C-layout (m74/m101): col = lane&31 = point, row = (r&3)+8*(r>>2)+4*(lane>>5), j = row+32t
// B in-lane bijection: per (kf,v,g):
//   j0 = 4g + (2v&3) + 8*(v>>1) + 16*(kf&1) + 32*(kf>>1), j1 = j0+1

// L1 epilogue (per t): z from Ch (b1 folded into MFMA); tangents = d * W1-cols.
// R13: tangent activations are single-level bf16 (cvtpk only, no lo split).
__device__ __forceinline__ void epilogue_L1(int t, const float4* __restrict__ w1q, int g,
                                            f32x16& Ch,
                                            u32x4 (&Bh)[3][4], u32x4 (&Bm0)[4], u32x4 (&Bl)[4]){
    #pragma unroll
    for (int kfh = 0; kfh < 2; ++kfh){
        const int kf = 2*t + kfh;
        #pragma unroll
        for (int v = 0; v < 4; ++v){
            const int r  = 8*kfh + 2*v;
            const int qi = (kf*4 + v)*2 + g;
            f32x2 z{Ch[r], Ch[r+1]};
            f32x2 h, d;
            selu_pair(z, h, d);
            float4 w = w1q[qi];             // {W1[j0,0],W1[j1,0],W1[j0,1],W1[j1,1]}
            f32x2 a = d * f32x2{w.x, w.y};
            f32x2 c = d * f32x2{w.z, w.w};
            unsigned int hi, mi, lo;
            split3_v(h, hi, mi, lo);
            Bh[0][kf][v] = hi; Bm0[kf][v] = mi; Bl[kf][v] = lo;
            Bh[1][kf][v] = cvtpk(a.x, a.y);
            Bh[2][kf][v] = cvtpk(c.x, c.y);
        }
    }
}

// Hidden layer, PATH-SPLIT form, phase order u0 -> u1 -> h (liveness-minimal,
// proven R6: 3 blocks/CU). sched_barrier(0) fences stop cross-phase hoisting
// (the R2 liveness-inflation failure mode).
// R13: tangent chains are 2-term (ah*Bh + am*Bh) — bf16-level tangent
// activations; residual ~2^-9 relative, smooth/linear (no discontinuity risk).
// z-path stays full 6-term. blds = LDS-resident bias table (broadcast, free).
template<bool FINAL>
__device__ __forceinline__ void hidden_layer(const unsigned int* wsrc, int lane4, int g,
                                             int fWh, int fWm, int fWl,
                                             const float* blds,
                                             const float4* __restrict__ w4q,
                                             u32x4 (&Bh)[3][4], u32x4 (&Bm0)[4], u32x4 (&Bl)[4],
                                             f32x2& dx0a, f32x2& dx1a, f32x2& tra){
    f32x16 Ch[2], Cu0[2], Cu1[2];

    // ---- phase-u0: tangent path 0, 2-term ----
    Cu0[0] = fzero(); Cu0[1] = fzero();
    __builtin_amdgcn_s_setprio(1);
    #pragma unroll
    for (int kf = 0; kf < 4; ++kf){
        #pragma unroll
        for (int t = 0; t < 2; ++t){
            const int q = t*4 + kf;
            bf16x8 ah = ldfrag(wsrc, fWh + q, lane4);
            bf16x8 am = ldfrag(wsrc, fWm + q, lane4);
            Cu0[t] = MFMA(am, BC(Bh[1][kf]),
                     MFMA(ah, BC(Bh[1][kf]), Cu0[t]));
        }
    }
    __builtin_amdgcn_sched_barrier(0);

    // ---- phase-u1: tangent path 1, 2-term ----
    Cu1[0] = fzero(); Cu1[1] = fzero();
    #pragma unroll
    for (int kf = 0; kf < 4; ++kf){
        #pragma unroll
        for (int t = 0; t < 2; ++t){
            const int q = t*4 + kf;
            bf16x8 ah = ldfrag(wsrc, fWh + q, lane4);
            bf16x8 am = ldfrag(wsrc, fWm + q, lane4);
            Cu1[t] = MFMA(am, BC(Bh[2][kf]),
                     MFMA(ah, BC(Bh[2][kf]), Cu1[t]));
        }
    }
    __builtin_amdgcn_sched_barrier(0);

    // ---- phase-h: z-path, 6-term (residual ~2^-24, unchanged) ----
    Ch[0] = fzero(); Ch[1] = fzero();
    #pragma unroll
    for (int kf = 0; kf < 4; ++kf){
        #pragma unroll
        for (int t = 0; t < 2; ++t){
            const int q = t*4 + kf;
            bf16x8 ah = ldfrag(wsrc, fWh + q, lane4);
            bf16x8 am = ldfrag(wsrc, fWm + q, lane4);
            bf16x8 al = ldfrag(wsrc, fWl + q, lane4);
            Ch[t] = MFMA(al, BC(Bh[0][kf]),
                    MFMA(am, BC(Bm0[kf]),
                    MFMA(ah, BC(Bl[kf]),
                    MFMA(am, BC(Bh[0][kf]),
                    MFMA(ah, BC(Bm0[kf]),
                    MFMA(ah, BC(Bh[0][kf]), Ch[t]))))));
        }
    }
    __builtin_amdgcn_s_setprio(0);
    __builtin_amdgcn_sched_barrier(0);

    // ---- epilogue (overwrites the SINGLE B buffer in place) ----
    #pragma unroll
    for (int kf = 0; kf < 4; ++kf){
        const int t = kf >> 1;
        #pragma unroll
        for (int v = 0; v < 4; ++v){
            const int r  = 8*(kf & 1) + 2*v;
            const int qi = (kf*4 + v)*2 + g;
            const int j0 = 4*g + ((2*v) & 3) + 8*(v >> 1) + 16*(kf & 1) + 32*(kf >> 1);
            float2 bb = *(const float2*)(blds + j0);    // LDS broadcast (2 addrs/wave)
            f32x2 z{Ch[t][r], Ch[t][r+1]};
            z = z + f32x2{bb.x, bb.y};
            f32x2 h, d;
            selu_pair(z, h, d);
            f32x2 a = d * f32x2{Cu0[t][r], Cu0[t][r+1]};
            f32x2 c = d * f32x2{Cu1[t][r], Cu1[t][r+1]};
            if (FINAL){
                float4 w = w4q[qi];         // {W4[0][j0],W4[0][j1],W4[1][j0],W4[1][j1]}
                f32x2 wxy{w.x, w.y}, wzw{w.z, w.w};
                dx0a = dx0a + wxy * h;
                dx1a = dx1a + wzw * h;
                tra  = tra  + wxy * a;
                tra  = tra  + wzw * c;
            } else {
                unsigned int hi, mi, lo;
                split3_v(h, hi, mi, lo);
                Bh[0][kf][v] = hi; Bm0[kf][v] = mi; Bl[kf][v] = lo;
                Bh[1][kf][v] = cvtpk(a.x, a.y);
                Bh[2][kf][v] = cvtpk(c.x, c.y);
            }
        }
    }
}

// ---------- one-time weight preprocessing (grid 22 x 64) ----------
__global__ void prep_kernel(const float* __restrict__ W1, const float* __restrict__ b1,
                            const float* __restrict__ W2, const float* __restrict__ W3,
                            const float* __restrict__ W4,
                            const float* __restrict__ b2, const float* __restrict__ b3)
{
    const int p  = blockIdx.x;
    const int ln = threadIdx.x;                 // 0..63
    const int g  = ln >> 5, l5 = ln & 31;
    if (p < 4){                                 // L1 packed frags
        const int t = p >> 1, var = p & 1;
        const int j = l5 + 32*t;
        const int lvl = (g == 0) ? 0 : (var == 0 ? 1 : 2);
        float vals[4] = { W1[j*3+0], W1[j*3+1], W1[j*3+2], b1[j] };
        unsigned int* ph = &g_frags[p*256 + ln*4];
        #pragma unroll
        for (int v = 0; v < 4; ++v){
            float a = (2*v   < 4) ? vals[2*v]   : 0.f;
            float b = (2*v+1 < 4) ? vals[2*v+1] : 0.f;
            unsigned int wa = (2*v   < 4) ? (unsigned int)lvl16(a, lvl) : 0u;
            unsigned int wb = (2*v+1 < 4) ? (unsigned int)lvl16(b, lvl) : 0u;
            ph[v] = wa | (wb << 16);
        }
    } else if (p < 20){                         // W2 / W3 triple-split frags
        const bool isW2 = (p < 12);
        const int q = p - (isW2 ? 4 : 12), t = q >> 2, kf = q & 3, m = l5 + 32*t;
        const float* __restrict__ Wg = isW2 ? W2 : W3;
        const int base = isW2 ? 4 : 29;
        unsigned int* ph = &g_frags[(base      + q)*256 + ln*4];
        unsigned int* pm = &g_frags[(base + 8  + q)*256 + ln*4];
        unsigned int* pl = &g_frags[(base + 16 + q)*256 + ln*4];
        #pragma unroll
        for (int v = 0; v < 4; ++v){
            int e0 = 2*v, e1 = 2*v + 1;
            int ja = 4*g + (e0&3) + 8*(e0>>2) + 16*(kf&1) + 32*(kf>>1);
            int jb = 4*g + (e1&3) + 8*(e1>>2) + 16*(kf&1) + 32*(kf>>1);
            float a = Wg[m*64 + ja], b = Wg[m*64 + jb];
            unsigned int ra = rne_bits(a), rb = rne_bits(b);
            ph[v] = (ra >> 16) | (rb & 0xffff0000u);
            float a1 = a - __uint_as_float(ra & 0xffff0000u);
            float b1v = b - __uint_as_float(rb & 0xffff0000u);
            unsigned int rma = rne_bits(a1), rmb = rne_bits(b1v);
            pm[v] = (rma >> 16) | (rmb & 0xffff0000u);
            float a2 = a1 - __uint_as_float(rma & 0xffff0000u);
            float b2v = b1v - __uint_as_float(rmb & 0xffff0000u);
            pl[v] = (rne_bits(a2) >> 16) | (rne_bits(b2v) & 0xffff0000u);
        }
    } else if (p == 20){                        // j-ordered fp32 quads
        if (ln < 32){
            const int qi = ln;                  // (kf*4+v)*2+g
            const int g2 = qi & 1, vv = (qi >> 1) & 3, kf = qi >> 3;
            const int j0 = 4*g2 + ((2*vv) & 3) + 8*(vv >> 1) + 16*(kf & 1) + 32*(kf >> 1);
            float4* w1q = (float4*)&g_frags[28*256];
            float4* w4q = w1q + 32;
            w1q[qi] = {W1[j0*3+0], W1[(j0+1)*3+0], W1[j0*3+1], W1[(j0+1)*3+1]};
            w4q[qi] = {W4[j0], W4[j0+1], W4[64+j0], W4[64+j0+1]};
        }
    } else {                                    // p == 21: bias tables (fp32 bits)
        g_frags[53*256      + ln] = __float_as_uint(b2[ln]);
        g_frags[53*256 + 64 + ln] = __float_as_uint(b3[ln]);
    }
}

// LDS image (29.5 KB): frags 0..27 (L1 + W2) + quads at frag 28 + b2|b3 (512 B)
#define OFF_Q (28*256)
#define OFF_B (29*256)
// launch_bounds(256,3): path-split keeps peak liveness within the 512/3=170
// budget (R6/R9/R11/R12: 3 blocks/CU, no spill).
__global__ __launch_bounds__(256, 3) void cnf_kernel(
    const float* __restrict__ tp, const float* __restrict__ x,
    const float* __restrict__ b4, float* __restrict__ out)
{
    __shared__ unsigned int ldsA[29*256 + 128]; // 30208 B

    // ---------- stage prepped frags + biases: vectorized global->LDS copy ----------
    {
        const u32x4* __restrict__ src = (const u32x4*)g_frags;
        u32x4* dst = (u32x4*)ldsA;
        for (int i = threadIdx.x; i < 29*64; i += 256) dst[i] = src[i];
        if (threadIdx.x < 32){
            ((u32x4*)(ldsA + OFF_B))[threadIdx.x] =
                ((const u32x4*)(g_frags + 53*256))[threadIdx.x];
        }
    }
    __syncthreads();

    const float4* w1q = (const float4*)&ldsA[OFF_Q];
    const float4* w4q = w1q + 32;
    const float*  b2l = (const float*)(ldsA + OFF_B);
    const float*  b3l = b2l + 64;
    const unsigned int* gW3 = g_frags + 29*256; // W3 bank stays in global (L1/L2-hot)

    // ---------- main (one 32-point group per wave; loop-free body, see ledger) ----------
    const int lane  = threadIdx.x & 63;
    const int g     = lane >> 5, l5 = lane & 31;
    const int lane4 = lane * 4;
    const int wid   = blockIdx.x * 4 + (threadIdx.x >> 6);

    const float ts  = tp[0];

    unsigned int tsh, tsm, tsl;
    split3s(ts, 1.0f, tsh, tsm, tsl);        // [ts, 1.0]; 1.0 exact

    const int n = wid*32 + l5;
    const float x0 = x[n*3 + 0], x1 = x[n*3 + 1];

    unsigned int xh, xm, xl;
    split3s(x0, x1, xh, xm, xl);
    const u32x4 Bp1 = { g ? xm : xh, g ? tsm : tsh, 0u, 0u };   // -> AhBh + AmBm
    const u32x4 Bp2 = { g ? xh : xm, g ? tsh : tsm, 0u, 0u };   // -> AhBm + AmBh
    const u32x4 Bp3 = { g ? xh : xl, g ? tsh : tsl, 0u, 0u };   // -> AhBl + AlBh

    u32x4 Bh[3][4], Bm0[4], Bl[4];          // SINGLE layer-interface buffer (80 regs)
    f32x2 dx0a = mk2(0.f), dx1a = mk2(0.f), tra = mk2(0.f);

    // ----- layer 1: z = W1ext @ [x0,x1,t,1] (6-term via 3 packed MFMAs) -----
    #pragma unroll
    for (int t = 0; t < 2; ++t){
        bf16x8 F1 = ldfrag(ldsA, 2*t,     lane4);   // [W1h | W1m]
        bf16x8 F3 = ldfrag(ldsA, 2*t + 1, lane4);   // [W1h | W1l]
        __builtin_amdgcn_s_setprio(1);
        f32x16 Ch = MFMA(F3, BC(Bp3), MFMA(F1, BC(Bp2), MFMA(F1, BC(Bp1), fzero())));
        __builtin_amdgcn_s_setprio(0);
        epilogue_L1(t, w1q, g, Ch, Bh, Bm0, Bl);
    }

    // ----- layer 2 (LDS frags) / layer 3 (global frags, fp32 L4 fused) -----
    hidden_layer<false>(ldsA, lane4, g, 4, 12, 20, b2l, nullptr, Bh, Bm0, Bl, dx0a, dx1a, tra);
    hidden_layer<true >(gW3,  lane4, g, 0,  8, 16, b3l, w4q,     Bh, Bm0, Bl, dx0a, dx1a, tra);

    // ----- pair-reduce + cross-half reduce -----
    float dx0 = dx0a.x + dx0a.y;
    float dx1 = dx1a.x + dx1a.y;
    float tr  = tra.x  + tra.y;
    dx0 += __shfl_xor(dx0, 32, 64);
    dx1 += __shfl_xor(dx1, 32, 64);
    tr  += __shfl_xor(tr,  32, 64);
    if (g == 0){
        const float b40 = b4[0], b41 = b4[1];   // loaded late: keeps them out of
        out[n*3 + 0] = dx0 + b40;               // the whole-kernel live range
        out[n*3 + 1] = dx1 + b41;
        out[n*3 + 2] = tr;
    }
}

extern "C" void kernel_launch(void* const* d_in, const int* in_sizes, int n_in,
                              void* d_out, int out_size, void* d_ws, size_t ws_size,
                              hipStream_t stream) {
    const float* t  = (const float*)d_in[0];
    const float* x  = (const float*)d_in[1];
    const float* W1 = (const float*)d_in[2];
    const float* b1 = (const float*)d_in[3];
    const float* W2 = (const float*)d_in[4];
    const float* b2 = (const float*)d_in[5];
    const float* W3 = (const float*)d_in[6];
    const float* b3 = (const float*)d_in[7];
    const float* W4 = (const float*)d_in[8];
    const float* b4 = (const float*)d_in[9];
    float* out = (float*)d_out;

    prep_kernel<<<22, 64, 0, stream>>>(W1, b1, W2, W3, W4, b2, b3);
    cnf_kernel<<<2048, 256, 0, stream>>>(t, x, b4, out);
}

// Round 14
// 55.055 us; speedup vs baseline: 2.9469x; 1.0256x over previous
//
#include <hip/hip_runtime.h>

#define SELU_S  1.0507009873554805f
#define SELU_SA (1.0507009873554805f * 1.6732632423543772f)

typedef __attribute__((ext_vector_type(8)))  short        bf16x8;
typedef __attribute__((ext_vector_type(16))) float        f32x16;
typedef __attribute__((ext_vector_type(2)))  float        f32x2;
typedef __attribute__((ext_vector_type(4)))  unsigned int u32x4;

#define MFMA(a,b,c) __builtin_amdgcn_mfma_f32_32x32x16_bf16((a),(b),(c),0,0,0)
#define BC(u) __builtin_bit_cast(bf16x8, (u))

// One-time prepped weight fragments (written by prep_kernel, read by cnf_kernel).
// Layout (frag = 256 u32 = 64 lanes x 16 B):
//   0..3   L1 packed frags
//   4..27  W2 h(4..11) | m(12..19) | l(20..27)
//   28     quads: w1q[32] float4 | w4q[32] float4 (1 KB)
//   29..52 W3 h(29..36) | m(37..44) | l(45..52)   <- stays in GLOBAL
//   53*256 .. +127 : b2[64] | b3[64] as f32 bits  <- staged to LDS
// Session ledger (proven, R1-R13):
//   R5/R6: path-split + launch_bounds(256,3) => 3 blocks/CU. The occupancy win.
//   R7:    W3-in-LDS breaks 3-block residency => keep W3 global.
//   R3/R4: wave-stagger / MFMA-chain reorders: null.
//   R8/R10: runtime loops => scratch corruption/spill. LOOP-FREE body is law.
//   R12:   drop am*Bl tangent term: -5.4%, absmax UNCHANGED 0.09375.
//   R13:   2-term tangent chains (bf16 tangent acts): 62.5 us disp / 56.5 bench,
//          absmax STILL 0.09375 => tangent precision does not touch max error.
//   R14 (this): merge u0+u1 into ONE phase — 4 independent 2-deep chains
//          (dependent spacing ~32cyc ≈ MFMA latency), ah/am loaded once for
//          both paths (-16 ds_read/layer), one fewer barrier. Per-chain
//          accumulation order unchanged => bit-identical output.
//   z-path stays full 6-term: its 2^-24 residual keeps SELU branch decisions
//   aligned with the fp32 reference (branch-window risk bounds further shaves).
__device__ __align__(16) unsigned int g_frags[53*256 + 128];

// ---- one-time (preprocessing) software RNE ----
__device__ __forceinline__ unsigned int rne_bits(float f){
    unsigned int b = __float_as_uint(f);
    return b + 0x7fffu + ((b >> 16) & 1u);
}
__device__ __forceinline__ unsigned short lvl16(float v, int lvl){
    unsigned int r0 = rne_bits(v);
    if (lvl == 0) return (unsigned short)(r0 >> 16);
    float v1 = v - __uint_as_float(r0 & 0xffff0000u);
    unsigned int r1 = rne_bits(v1);
    if (lvl == 1) return (unsigned short)(r1 >> 16);
    float v2 = v1 - __uint_as_float(r1 & 0xffff0000u);
    return (unsigned short)(rne_bits(v2) >> 16);
}

// ---- hot-path split primitive ----
__device__ __forceinline__ unsigned int cvtpk(float a, float b){
    unsigned int r;
    asm("v_cvt_pk_bf16_f32 %0, %1, %2" : "=v"(r) : "v"(a), "v"(b));
    return r;
}
__device__ __forceinline__ f32x2 unpk2(unsigned int p){
    f32x2 r;
    r.x = __uint_as_float(p << 16);
    r.y = __uint_as_float(p & 0xffff0000u);
    return r;
}
__device__ __forceinline__ f32x2 mk2(float v){ return f32x2{v, v}; }

__device__ __forceinline__ void split3_v(f32x2 v,
                                         unsigned int& hi, unsigned int& mi, unsigned int& lo){
    hi = cvtpk(v.x, v.y);
    f32x2 r1 = v - unpk2(hi);
    mi = cvtpk(r1.x, r1.y);
    f32x2 r2 = r1 - unpk2(mi);
    lo = cvtpk(r2.x, r2.y);                    // total residual <= 2^-24|v|
}
__device__ __forceinline__ void split3s(float a, float b,
                                        unsigned int& hi, unsigned int& mi, unsigned int& lo){
    split3_v(f32x2{a, b}, hi, mi, lo);
}

__device__ __forceinline__ f32x16 fzero(){
    f32x16 z;
    #pragma unroll
    for (int i = 0; i < 16; ++i) z[i] = 0.f;
    return z;
}

// works for both LDS-derived and global pointers (addrspace recovered after inlining)
__device__ __forceinline__ bf16x8 ldfrag(const unsigned int* src, int fid, int lane4){
    u32x4 u = *(const u32x4*)(src + fid*256 + lane4);
    return __builtin_bit_cast(bf16x8, u);
}

// SELU value+derivative for a packed pair
__device__ __forceinline__ void selu_pair(f32x2 z, f32x2& h, f32x2& d){
    f32x2 e{__expf(z.x), __expf(z.y)};
    f32x2 hn = e * mk2(SELU_SA) - mk2(SELU_SA);
    f32x2 hp = z * mk2(SELU_S);
    f32x2 dn = e * mk2(SELU_SA);
    h.x = z.x > 0.f ? hp.x : hn.x;
    h.y = z.y > 0.f ? hp.y : hn.y;
    d.x = z.x > 0.f ? SELU_S : dn.x;
    d.y = z.y > 0.f ? SELU_S : dn.y;
}

// C-layout (m74/m101): col = lane&31 = point, row = (r&3)+8*(r>>2)+4*(lane>>5), j = row+32t
// B in-lane bijection: per (kf,v,g):
//   j0 = 4g + (2v&3) + 8*(v>>1) + 16*(kf&1) + 32*(kf>>1), j1 = j0+1

// L1 epilogue (per t): z from Ch (b1 folded into MFMA); tangents = d * W1-cols.
// Tangent activations are single-level bf16 (cvtpk only, no lo split).
__device__ __forceinline__ void epilogue_L1(int t, const float4* __restrict__ w1q, int g,
                                            f32x16& Ch,
                                            u32x4 (&Bh)[3][4], u32x4 (&Bm0)[4], u32x4 (&Bl)[4]){
    #pragma unroll
    for (int kfh = 0; kfh < 2; ++kfh){
        const int kf = 2*t + kfh;
        #pragma unroll
        for (int v = 0; v < 4; ++v){
            const int r  = 8*kfh + 2*v;
            const int qi = (kf*4 + v)*2 + g;
            f32x2 z{Ch[r], Ch[r+1]};
            f32x2 h, d;
            selu_pair(z, h, d);
            float4 w = w1q[qi];             // {W1[j0,0],W1[j1,0],W1[j0,1],W1[j1,1]}
            f32x2 a = d * f32x2{w.x, w.y};
            f32x2 c = d * f32x2{w.z, w.w};
            unsigned int hi, mi, lo;
            split3_v(h, hi, mi, lo);
            Bh[0][kf][v] = hi; Bm0[kf][v] = mi; Bl[kf][v] = lo;
            Bh[1][kf][v] = cvtpk(a.x, a.y);
            Bh[2][kf][v] = cvtpk(c.x, c.y);
        }
    }
}

// Hidden layer, PATH-SPLIT form, phase order (u0+u1 merged) -> h:
//   merged-u: 32 MFMA into Cu0,Cu1 — 4 independent 2-deep chains, ah/am
//             loaded once for both tangent paths (R14).
//   phase-h : 48 MFMA into Ch — full 6-term z-path (residual ~2^-24).
// Liveness: merged-u = B(80)+Cu(64)+frags ~160 <= 170 budget; phase-h
// unchanged. sched_barrier(0) fences stop cross-phase hoisting (R2 lesson).
// blds = LDS-resident bias table (2-address broadcast read, free).
template<bool FINAL>
__device__ __forceinline__ void hidden_layer(const unsigned int* wsrc, int lane4, int g,
                                             int fWh, int fWm, int fWl,
                                             const float* blds,
                                             const float4* __restrict__ w4q,
                                             u32x4 (&Bh)[3][4], u32x4 (&Bm0)[4], u32x4 (&Bl)[4],
                                             f32x2& dx0a, f32x2& dx1a, f32x2& tra){
    f32x16 Ch[2], Cu0[2], Cu1[2];

    // ---- merged tangent phase: u0 and u1, 2-term chains, shared frags ----
    Cu0[0] = fzero(); Cu0[1] = fzero();
    Cu1[0] = fzero(); Cu1[1] = fzero();
    __builtin_amdgcn_s_setprio(1);
    #pragma unroll
    for (int kf = 0; kf < 4; ++kf){
        #pragma unroll
        for (int t = 0; t < 2; ++t){
            const int q = t*4 + kf;
            bf16x8 ah = ldfrag(wsrc, fWh + q, lane4);
            bf16x8 am = ldfrag(wsrc, fWm + q, lane4);
            Cu0[t] = MFMA(am, BC(Bh[1][kf]),
                     MFMA(ah, BC(Bh[1][kf]), Cu0[t]));
            Cu1[t] = MFMA(am, BC(Bh[2][kf]),
                     MFMA(ah, BC(Bh[2][kf]), Cu1[t]));
        }
    }
    __builtin_amdgcn_sched_barrier(0);

    // ---- phase-h: z-path, 6-term (residual ~2^-24, unchanged) ----
    Ch[0] = fzero(); Ch[1] = fzero();
    #pragma unroll
    for (int kf = 0; kf < 4; ++kf){
        #pragma unroll
        for (int t = 0; t < 2; ++t){
            const int q = t*4 + kf;
            bf16x8 ah = ldfrag(wsrc, fWh + q, lane4);
            bf16x8 am = ldfrag(wsrc, fWm + q, lane4);
            bf16x8 al = ldfrag(wsrc, fWl + q, lane4);
            Ch[t] = MFMA(al, BC(Bh[0][kf]),
                    MFMA(am, BC(Bm0[kf]),
                    MFMA(ah, BC(Bl[kf]),
                    MFMA(am, BC(Bh[0][kf]),
                    MFMA(ah, BC(Bm0[kf]),
                    MFMA(ah, BC(Bh[0][kf]), Ch[t]))))));
        }
    }
    __builtin_amdgcn_s_setprio(0);
    __builtin_amdgcn_sched_barrier(0);

    // ---- epilogue (overwrites the SINGLE B buffer in place) ----
    #pragma unroll
    for (int kf = 0; kf < 4; ++kf){
        const int t = kf >> 1;
        #pragma unroll
        for (int v = 0; v < 4; ++v){
            const int r  = 8*(kf & 1) + 2*v;
            const int qi = (kf*4 + v)*2 + g;
            const int j0 = 4*g + ((2*v) & 3) + 8*(v >> 1) + 16*(kf & 1) + 32*(kf >> 1);
            float2 bb = *(const float2*)(blds + j0);    // LDS broadcast (2 addrs/wave)
            f32x2 z{Ch[t][r], Ch[t][r+1]};
            z = z + f32x2{bb.x, bb.y};
            f32x2 h, d;
            selu_pair(z, h, d);
            f32x2 a = d * f32x2{Cu0[t][r], Cu0[t][r+1]};
            f32x2 c = d * f32x2{Cu1[t][r], Cu1[t][r+1]};
            if (FINAL){
                float4 w = w4q[qi];         // {W4[0][j0],W4[0][j1],W4[1][j0],W4[1][j1]}
                f32x2 wxy{w.x, w.y}, wzw{w.z, w.w};
                dx0a = dx0a + wxy * h;
                dx1a = dx1a + wzw * h;
                tra  = tra  + wxy * a;
                tra  = tra  + wzw * c;
            } else {
                unsigned int hi, mi, lo;
                split3_v(h, hi, mi, lo);
                Bh[0][kf][v] = hi; Bm0[kf][v] = mi; Bl[kf][v] = lo;
                Bh[1][kf][v] = cvtpk(a.x, a.y);
                Bh[2][kf][v] = cvtpk(c.x, c.y);
            }
        }
    }
}

// ---------- one-time weight preprocessing (grid 22 x 64) ----------
__global__ void prep_kernel(const float* __restrict__ W1, const float* __restrict__ b1,
                            const float* __restrict__ W2, const float* __restrict__ W3,
                            const float* __restrict__ W4,
                            const float* __restrict__ b2, const float* __restrict__ b3)
{
    const int p  = blockIdx.x;
    const int ln = threadIdx.x;                 // 0..63
    const int g  = ln >> 5, l5 = ln & 31;
    if (p < 4){                                 // L1 packed frags
        const int t = p >> 1, var = p & 1;
        const int j = l5 + 32*t;
        const int lvl = (g == 0) ? 0 : (var == 0 ? 1 : 2);
        float vals[4] = { W1[j*3+0], W1[j*3+1], W1[j*3+2], b1[j] };
        unsigned int* ph = &g_frags[p*256 + ln*4];
        #pragma unroll
        for (int v = 0; v < 4; ++v){
            float a = (2*v   < 4) ? vals[2*v]   : 0.f;
            float b = (2*v+1 < 4) ? vals[2*v+1] : 0.f;
            unsigned int wa = (2*v   < 4) ? (unsigned int)lvl16(a, lvl) : 0u;
            unsigned int wb = (2*v+1 < 4) ? (unsigned int)lvl16(b, lvl) : 0u;
            ph[v] = wa | (wb << 16);
        }
    } else if (p < 20){                         // W2 / W3 triple-split frags
        const bool isW2 = (p < 12);
        const int q = p - (isW2 ? 4 : 12), t = q >> 2, kf = q & 3, m = l5 + 32*t;
        const float* __restrict__ Wg = isW2 ? W2 : W3;
        const int base = isW2 ? 4 : 29;
        unsigned int* ph = &g_frags[(base      + q)*256 + ln*4];
        unsigned int* pm = &g_frags[(base + 8  + q)*256 + ln*4];
        unsigned int* pl = &g_frags[(base + 16 + q)*256 + ln*4];
        #pragma unroll
        for (int v = 0; v < 4; ++v){
            int e0 = 2*v, e1 = 2*v + 1;
            int ja = 4*g + (e0&3) + 8*(e0>>2) + 16*(kf&1) + 32*(kf>>1);
            int jb = 4*g + (e1&3) + 8*(e1>>2) + 16*(kf&1) + 32*(kf>>1);
            float a = Wg[m*64 + ja], b = Wg[m*64 + jb];
            unsigned int ra = rne_bits(a), rb = rne_bits(b);
            ph[v] = (ra >> 16) | (rb & 0xffff0000u);
            float a1 = a - __uint_as_float(ra & 0xffff0000u);
            float b1v = b - __uint_as_float(rb & 0xffff0000u);
            unsigned int rma = rne_bits(a1), rmb = rne_bits(b1v);
            pm[v] = (rma >> 16) | (rmb & 0xffff0000u);
            float a2 = a1 - __uint_as_float(rma & 0xffff0000u);
            float b2v = b1v - __uint_as_float(rmb & 0xffff0000u);
            pl[v] = (rne_bits(a2) >> 16) | (rne_bits(b2v) & 0xffff0000u);
        }
    } else if (p == 20){                        // j-ordered fp32 quads
        if (ln < 32){
            const int qi = ln;                  // (kf*4+v)*2+g
            const int g2 = qi & 1, vv = (qi >> 1) & 3, kf = qi >> 3;
            const int j0 = 4*g2 + ((2*vv) & 3) + 8*(vv >> 1) + 16*(kf & 1) + 32*(kf >> 1);
            float4* w1q = (float4*)&g_frags[28*256];
            float4* w4q = w1q + 32;
            w1q[qi] = {W1[j0*3+0], W1[(j0+1)*3+0], W1[j0*3+1], W1[(j0+1)*3+1]};
            w4q[qi] = {W4[j0], W4[j0+1], W4[64+j0], W4[64+j0+1]};
        }
    } else {                                    // p == 21: bias tables (fp32 bits)
        g_frags[53*256      + ln] = __float_as_uint(b2[ln]);
        g_frags[53*256 + 64 + ln] = __float_as_uint(b3[ln]);
    }
}

// LDS image (29.5 KB): frags 0..27 (L1 + W2) + quads at frag 28 + b2|b3 (512 B)
#define OFF_Q (28*256)
#define OFF_B (29*256)
// launch_bounds(256,3): path-split keeps peak liveness within the 512/3=170
// budget (R6/R9/R11/R12/R13: 3 blocks/CU, no spill).
__global__ __launch_bounds__(256, 3) void cnf_kernel(
    const float* __restrict__ tp, const float* __restrict__ x,
    const float* __restrict__ b4, float* __restrict__ out)
{
    __shared__ unsigned int ldsA[29*256 + 128]; // 30208 B

    // ---------- stage prepped frags + biases: vectorized global->LDS copy ----------
    {
        const u32x4* __restrict__ src = (const u32x4*)g_frags;
        u32x4* dst = (u32x4*)ldsA;
        for (int i = threadIdx.x; i < 29*64; i += 256) dst[i] = src[i];
        if (threadIdx.x < 32){
            ((u32x4*)(ldsA + OFF_B))[threadIdx.x] =
                ((const u32x4*)(g_frags + 53*256))[threadIdx.x];
        }
    }
    __syncthreads();

    const float4* w1q = (const float4*)&ldsA[OFF_Q];
    const float4* w4q = w1q + 32;
    const float*  b2l = (const float*)(ldsA + OFF_B);
    const float*  b3l = b2l + 64;
    const unsigned int* gW3 = g_frags + 29*256; // W3 bank stays in global (L1/L2-hot)

    // ---------- main (one 32-point group per wave; loop-free body, see ledger) ----------
    const int lane  = threadIdx.x & 63;
    const int g     = lane >> 5, l5 = lane & 31;
    const int lane4 = lane * 4;
    const int wid   = blockIdx.x * 4 + (threadIdx.x >> 6);

    const float ts  = tp[0];

    unsigned int tsh, tsm, tsl;
    split3s(ts, 1.0f, tsh, tsm, tsl);        // [ts, 1.0]; 1.0 exact

    const int n = wid*32 + l5;
    const float x0 = x[n*3 + 0], x1 = x[n*3 + 1];

    unsigned int xh, xm, xl;
    split3s(x0, x1, xh, xm, xl);
    const u32x4 Bp1 = { g ? xm : xh, g ? tsm : tsh, 0u, 0u };   // -> AhBh + AmBm
    const u32x4 Bp2 = { g ? xh : xm, g ? tsh : tsm, 0u, 0u };   // -> AhBm + AmBh
    const u32x4 Bp3 = { g ? xh : xl, g ? tsh : tsl, 0u, 0u };   // -> AhBl + AlBh

    u32x4 Bh[3][4], Bm0[4], Bl[4];          // SINGLE layer-interface buffer (80 regs)
    f32x2 dx0a = mk2(0.f), dx1a = mk2(0.f), tra = mk2(0.f);

    // ----- layer 1: z = W1ext @ [x0,x1,t,1] (6-term via 3 packed MFMAs) -----
    #pragma unroll
    for (int t = 0; t < 2; ++t){
        bf16x8 F1 = ldfrag(ldsA, 2*t,     lane4);   // [W1h | W1m]
        bf16x8 F3 = ldfrag(ldsA, 2*t + 1, lane4);   // [W1h | W1l]
        __builtin_amdgcn_s_setprio(1);
        f32x16 Ch = MFMA(F3, BC(Bp3), MFMA(F1, BC(Bp2), MFMA(F1, BC(Bp1), fzero())));
        __builtin_amdgcn_s_setprio(0);
        epilogue_L1(t, w1q, g, Ch, Bh, Bm0, Bl);
    }

    // ----- layer 2 (LDS frags) / layer 3 (global frags, fp32 L4 fused) -----
    hidden_layer<false>(ldsA, lane4, g, 4, 12, 20, b2l, nullptr, Bh, Bm0, Bl, dx0a, dx1a, tra);
    hidden_layer<true >(gW3,  lane4, g, 0,  8, 16, b3l, w4q,     Bh, Bm0, Bl, dx0a, dx1a, tra);

    // ----- pair-reduce + cross-half reduce -----
    float dx0 = dx0a.x + dx0a.y;
    float dx1 = dx1a.x + dx1a.y;
    float tr  = tra.x  + tra.y;
    dx0 += __shfl_xor(dx0, 32, 64);
    dx1 += __shfl_xor(dx1, 32, 64);
    tr  += __shfl_xor(tr,  32, 64);
    if (g == 0){
        const float b40 = b4[0], b41 = b4[1];   // loaded late: keeps them out of
        out[n*3 + 0] = dx0 + b40;               // the whole-kernel live range
        out[n*3 + 1] = dx1 + b41;
        out[n*3 + 2] = tr;
    }
}

extern "C" void kernel_launch(void* const* d_in, const int* in_sizes, int n_in,
                              void* d_out, int out_size, void* d_ws, size_t ws_size,
                              hipStream_t stream) {
    const float* t  = (const float*)d_in[0];
    const float* x  = (const float*)d_in[1];
    const float* W1 = (const float*)d_in[2];
    const float* b1 = (const float*)d_in[3];
    const float* W2 = (const float*)d_in[4];
    const float* b2 = (const float*)d_in[5];
    const float* W3 = (const float*)d_in[6];
    const float* b3 = (const float*)d_in[7];
    const float* W4 = (const float*)d_in[8];
    const float* b4 = (const float*)d_in[9];
    float* out = (float*)d_out;

    prep_kernel<<<22, 64, 0, stream>>>(W1, b1, W2, W3, W4, b2, b3);
    cnf_kernel<<<2048, 256, 0, stream>>>(t, x, b4, out);
}

// Round 15
// 50.171 us; speedup vs baseline: 3.2338x; 1.0973x over previous
//
#include <hip/hip_runtime.h>

#define SELU_S  1.0507009873554805f
#define SELU_SA (1.0507009873554805f * 1.6732632423543772f)

typedef __attribute__((ext_vector_type(8)))  short        bf16x8;
typedef __attribute__((ext_vector_type(16))) float        f32x16;
typedef __attribute__((ext_vector_type(2)))  float        f32x2;
typedef __attribute__((ext_vector_type(4)))  unsigned int u32x4;

#define MFMA(a,b,c) __builtin_amdgcn_mfma_f32_32x32x16_bf16((a),(b),(c),0,0,0)
#define BC(u) __builtin_bit_cast(bf16x8, (u))

// One-time prepped weight fragments (written by prep_kernel, read by cnf_kernel).
// Layout (frag = 256 u32 = 64 lanes x 16 B):
//   0..3   L1 packed frags
//   4..27  W2 h(4..11) | m(12..19) | l(20..27)
//   28     quads: w1q[32] float4 | w4q[32] float4 (1 KB)
//   29..52 W3 h(29..36) | m(37..44) | l(45..52)   <- stays in GLOBAL
//   53*256 .. +127 : b2[64] | b3[64] as f32 bits  <- staged to LDS
// Session ledger (proven, R1-R14):
//   R5/R6: path-split + launch_bounds(256,3) => 3 blocks/CU. The occupancy win.
//   R7:    W3-in-LDS breaks 3-block residency => keep W3 global.
//   R3/R4: wave-stagger / MFMA-chain reorders: null.
//   R8/R10: runtime loops => scratch corruption/spill. LOOP-FREE body is law.
//   R12:   drop am*Bl tangent term: -5.4%, absmax UNCHANGED 0.09375.
//   R13:   2-term tangent chains (bf16 tangent acts): absmax STILL 0.09375.
//   R14:   merge u0+u1 into one phase (shared frags): 61.5 disp / 55.0 bench,
//          bit-identical. absmax frozen through ALL tangent shaves => argmax
//          point is dx-path (z-path) only.
//   R15 (this): 1-term tangent chains — pure bf16 tangent matmul (ah*Bu).
//          166->134 MFMA (-19%), no am loads in tangent phase, 1-deep
//          fully-independent chains. Tangent rel err ~2^-8.5 (was 2^-9),
//          ~3 orders below the 0.019 absmax margin.
//   z-path stays full 6-term: its 2^-24 residual keeps SELU branch decisions
//   aligned with the fp32 reference (branch-window risk bounds further shaves).
__device__ __align__(16) unsigned int g_frags[53*256 + 128];

// ---- one-time (preprocessing) software RNE ----
__device__ __forceinline__ unsigned int rne_bits(float f){
    unsigned int b = __float_as_uint(f);
    return b + 0x7fffu + ((b >> 16) & 1u);
}
__device__ __forceinline__ unsigned short lvl16(float v, int lvl){
    unsigned int r0 = rne_bits(v);
    if (lvl == 0) return (unsigned short)(r0 >> 16);
    float v1 = v - __uint_as_float(r0 & 0xffff0000u);
    unsigned int r1 = rne_bits(v1);
    if (lvl == 1) return (unsigned short)(r1 >> 16);
    float v2 = v1 - __uint_as_float(r1 & 0xffff0000u);
    return (unsigned short)(rne_bits(v2) >> 16);
}

// ---- hot-path split primitive ----
__device__ __forceinline__ unsigned int cvtpk(float a, float b){
    unsigned int r;
    asm("v_cvt_pk_bf16_f32 %0, %1, %2" : "=v"(r) : "v"(a), "v"(b));
    return r;
}
__device__ __forceinline__ f32x2 unpk2(unsigned int p){
    f32x2 r;
    r.x = __uint_as_float(p << 16);
    r.y = __uint_as_float(p & 0xffff0000u);
    return r;
}
__device__ __forceinline__ f32x2 mk2(float v){ return f32x2{v, v}; }

__device__ __forceinline__ void split3_v(f32x2 v,
                                         unsigned int& hi, unsigned int& mi, unsigned int& lo){
    hi = cvtpk(v.x, v.y);
    f32x2 r1 = v - unpk2(hi);
    mi = cvtpk(r1.x, r1.y);
    f32x2 r2 = r1 - unpk2(mi);
    lo = cvtpk(r2.x, r2.y);                    // total residual <= 2^-24|v|
}
__device__ __forceinline__ void split3s(float a, float b,
                                        unsigned int& hi, unsigned int& mi, unsigned int& lo){
    split3_v(f32x2{a, b}, hi, mi, lo);
}

__device__ __forceinline__ f32x16 fzero(){
    f32x16 z;
    #pragma unroll
    for (int i = 0; i < 16; ++i) z[i] = 0.f;
    return z;
}

// works for both LDS-derived and global pointers (addrspace recovered after inlining)
__device__ __forceinline__ bf16x8 ldfrag(const unsigned int* src, int fid, int lane4){
    u32x4 u = *(const u32x4*)(src + fid*256 + lane4);
    return __builtin_bit_cast(bf16x8, u);
}

// SELU value+derivative for a packed pair
__device__ __forceinline__ void selu_pair(f32x2 z, f32x2& h, f32x2& d){
    f32x2 e{__expf(z.x), __expf(z.y)};
    f32x2 hn = e * mk2(SELU_SA) - mk2(SELU_SA);
    f32x2 hp = z * mk2(SELU_S);
    f32x2 dn = e * mk2(SELU_SA);
    h.x = z.x > 0.f ? hp.x : hn.x;
    h.y = z.y > 0.f ? hp.y : hn.y;
    d.x = z.x > 0.f ? SELU_S : dn.x;
    d.y = z.y > 0.f ? SELU_S : dn.y;
}

// C-layout (m74/m101): col = lane&31 = point, row = (r&3)+8*(r>>2)+4*(lane>>5), j = row+32t
// B in-lane bijection: per (kf,v,g):
//   j0 = 4g + (2v&3) + 8*(v>>1) + 16*(kf&1) + 32*(kf>>1), j1 = j0+1

// L1 epilogue (per t): z from Ch (b1 folded into MFMA); tangents = d * W1-cols.
// Tangent activations are single-level bf16 (cvtpk only, no lo split).
__device__ __forceinline__ void epilogue_L1(int t, const float4* __restrict__ w1q, int g,
                                            f32x16& Ch,
                                            u32x4 (&Bh)[3][4], u32x4 (&Bm0)[4], u32x4 (&Bl)[4]){
    #pragma unroll
    for (int kfh = 0; kfh < 2; ++kfh){
        const int kf = 2*t + kfh;
        #pragma unroll
        for (int v = 0; v < 4; ++v){
            const int r  = 8*kfh + 2*v;
            const int qi = (kf*4 + v)*2 + g;
            f32x2 z{Ch[r], Ch[r+1]};
            f32x2 h, d;
            selu_pair(z, h, d);
            float4 w = w1q[qi];             // {W1[j0,0],W1[j1,0],W1[j0,1],W1[j1,1]}
            f32x2 a = d * f32x2{w.x, w.y};
            f32x2 c = d * f32x2{w.z, w.w};
            unsigned int hi, mi, lo;
            split3_v(h, hi, mi, lo);
            Bh[0][kf][v] = hi; Bm0[kf][v] = mi; Bl[kf][v] = lo;
            Bh[1][kf][v] = cvtpk(a.x, a.y);
            Bh[2][kf][v] = cvtpk(c.x, c.y);
        }
    }
}

// Hidden layer, PATH-SPLIT form, phase order (merged tangent) -> h:
//   tangent phase: 16 MFMA — ONE term per path (pure bf16: ah*Bu), 4
//                  independent 1-deep chains per iter, ah loaded once (R15).
//   phase-h     : 48 MFMA into Ch — full 6-term z-path (residual ~2^-24).
// Liveness: tangent = B(80)+Cu(64)+frag ~152 <= 170 budget; phase-h
// unchanged. sched_barrier(0) fences stop cross-phase hoisting (R2 lesson).
// blds = LDS-resident bias table (2-address broadcast read, free).
template<bool FINAL>
__device__ __forceinline__ void hidden_layer(const unsigned int* wsrc, int lane4, int g,
                                             int fWh, int fWm, int fWl,
                                             const float* blds,
                                             const float4* __restrict__ w4q,
                                             u32x4 (&Bh)[3][4], u32x4 (&Bm0)[4], u32x4 (&Bl)[4],
                                             f32x2& dx0a, f32x2& dx1a, f32x2& tra){
    f32x16 Ch[2], Cu0[2], Cu1[2];

    // ---- merged tangent phase: 1-term chains (pure bf16), shared ah frag ----
    Cu0[0] = fzero(); Cu0[1] = fzero();
    Cu1[0] = fzero(); Cu1[1] = fzero();
    __builtin_amdgcn_s_setprio(1);
    #pragma unroll
    for (int kf = 0; kf < 4; ++kf){
        #pragma unroll
        for (int t = 0; t < 2; ++t){
            const int q = t*4 + kf;
            bf16x8 ah = ldfrag(wsrc, fWh + q, lane4);
            Cu0[t] = MFMA(ah, BC(Bh[1][kf]), Cu0[t]);
            Cu1[t] = MFMA(ah, BC(Bh[2][kf]), Cu1[t]);
        }
    }
    __builtin_amdgcn_sched_barrier(0);

    // ---- phase-h: z-path, 6-term (residual ~2^-24, unchanged) ----
    Ch[0] = fzero(); Ch[1] = fzero();
    #pragma unroll
    for (int kf = 0; kf < 4; ++kf){
        #pragma unroll
        for (int t = 0; t < 2; ++t){
            const int q = t*4 + kf;
            bf16x8 ah = ldfrag(wsrc, fWh + q, lane4);
            bf16x8 am = ldfrag(wsrc, fWm + q, lane4);
            bf16x8 al = ldfrag(wsrc, fWl + q, lane4);
            Ch[t] = MFMA(al, BC(Bh[0][kf]),
                    MFMA(am, BC(Bm0[kf]),
                    MFMA(ah, BC(Bl[kf]),
                    MFMA(am, BC(Bh[0][kf]),
                    MFMA(ah, BC(Bm0[kf]),
                    MFMA(ah, BC(Bh[0][kf]), Ch[t]))))));
        }
    }
    __builtin_amdgcn_s_setprio(0);
    __builtin_amdgcn_sched_barrier(0);

    // ---- epilogue (overwrites the SINGLE B buffer in place) ----
    #pragma unroll
    for (int kf = 0; kf < 4; ++kf){
        const int t = kf >> 1;
        #pragma unroll
        for (int v = 0; v < 4; ++v){
            const int r  = 8*(kf & 1) + 2*v;
            const int qi = (kf*4 + v)*2 + g;
            const int j0 = 4*g + ((2*v) & 3) + 8*(v >> 1) + 16*(kf & 1) + 32*(kf >> 1);
            float2 bb = *(const float2*)(blds + j0);    // LDS broadcast (2 addrs/wave)
            f32x2 z{Ch[t][r], Ch[t][r+1]};
            z = z + f32x2{bb.x, bb.y};
            f32x2 h, d;
            selu_pair(z, h, d);
            f32x2 a = d * f32x2{Cu0[t][r], Cu0[t][r+1]};
            f32x2 c = d * f32x2{Cu1[t][r], Cu1[t][r+1]};
            if (FINAL){
                float4 w = w4q[qi];         // {W4[0][j0],W4[0][j1],W4[1][j0],W4[1][j1]}
                f32x2 wxy{w.x, w.y}, wzw{w.z, w.w};
                dx0a = dx0a + wxy * h;
                dx1a = dx1a + wzw * h;
                tra  = tra  + wxy * a;
                tra  = tra  + wzw * c;
            } else {
                unsigned int hi, mi, lo;
                split3_v(h, hi, mi, lo);
                Bh[0][kf][v] = hi; Bm0[kf][v] = mi; Bl[kf][v] = lo;
                Bh[1][kf][v] = cvtpk(a.x, a.y);
                Bh[2][kf][v] = cvtpk(c.x, c.y);
            }
        }
    }
}

// ---------- one-time weight preprocessing (grid 22 x 64) ----------
__global__ void prep_kernel(const float* __restrict__ W1, const float* __restrict__ b1,
                            const float* __restrict__ W2, const float* __restrict__ W3,
                            const float* __restrict__ W4,
                            const float* __restrict__ b2, const float* __restrict__ b3)
{
    const int p  = blockIdx.x;
    const int ln = threadIdx.x;                 // 0..63
    const int g  = ln >> 5, l5 = ln & 31;
    if (p < 4){                                 // L1 packed frags
        const int t = p >> 1, var = p & 1;
        const int j = l5 + 32*t;
        const int lvl = (g == 0) ? 0 : (var == 0 ? 1 : 2);
        float vals[4] = { W1[j*3+0], W1[j*3+1], W1[j*3+2], b1[j] };
        unsigned int* ph = &g_frags[p*256 + ln*4];
        #pragma unroll
        for (int v = 0; v < 4; ++v){
            float a = (2*v   < 4) ? vals[2*v]   : 0.f;
            float b = (2*v+1 < 4) ? vals[2*v+1] : 0.f;
            unsigned int wa = (2*v   < 4) ? (unsigned int)lvl16(a, lvl) : 0u;
            unsigned int wb = (2*v+1 < 4) ? (unsigned int)lvl16(b, lvl) : 0u;
            ph[v] = wa | (wb << 16);
        }
    } else if (p < 20){                         // W2 / W3 triple-split frags
        const bool isW2 = (p < 12);
        const int q = p - (isW2 ? 4 : 12), t = q >> 2, kf = q & 3, m = l5 + 32*t;
        const float* __restrict__ Wg = isW2 ? W2 : W3;
        const int base = isW2 ? 4 : 29;
        unsigned int* ph = &g_frags[(base      + q)*256 + ln*4];
        unsigned int* pm = &g_frags[(base + 8  + q)*256 + ln*4];
        unsigned int* pl = &g_frags[(base + 16 + q)*256 + ln*4];
        #pragma unroll
        for (int v = 0; v < 4; ++v){
            int e0 = 2*v, e1 = 2*v + 1;
            int ja = 4*g + (e0&3) + 8*(e0>>2) + 16*(kf&1) + 32*(kf>>1);
            int jb = 4*g + (e1&3) + 8*(e1>>2) + 16*(kf&1) + 32*(kf>>1);
            float a = Wg[m*64 + ja], b = Wg[m*64 + jb];
            unsigned int ra = rne_bits(a), rb = rne_bits(b);
            ph[v] = (ra >> 16) | (rb & 0xffff0000u);
            float a1 = a - __uint_as_float(ra & 0xffff0000u);
            float b1v = b - __uint_as_float(rb & 0xffff0000u);
            unsigned int rma = rne_bits(a1), rmb = rne_bits(b1v);
            pm[v] = (rma >> 16) | (rmb & 0xffff0000u);
            float a2 = a1 - __uint_as_float(rma & 0xffff0000u);
            float b2v = b1v - __uint_as_float(rmb & 0xffff0000u);
            pl[v] = (rne_bits(a2) >> 16) | (rne_bits(b2v) & 0xffff0000u);
        }
    } else if (p == 20){                        // j-ordered fp32 quads
        if (ln < 32){
            const int qi = ln;                  // (kf*4+v)*2+g
            const int g2 = qi & 1, vv = (qi >> 1) & 3, kf = qi >> 3;
            const int j0 = 4*g2 + ((2*vv) & 3) + 8*(vv >> 1) + 16*(kf & 1) + 32*(kf >> 1);
            float4* w1q = (float4*)&g_frags[28*256];
            float4* w4q = w1q + 32;
            w1q[qi] = {W1[j0*3+0], W1[(j0+1)*3+0], W1[j0*3+1], W1[(j0+1)*3+1]};
            w4q[qi] = {W4[j0], W4[j0+1], W4[64+j0], W4[64+j0+1]};
        }
    } else {                                    // p == 21: bias tables (fp32 bits)
        g_frags[53*256      + ln] = __float_as_uint(b2[ln]);
        g_frags[53*256 + 64 + ln] = __float_as_uint(b3[ln]);
    }
}

// LDS image (29.5 KB): frags 0..27 (L1 + W2) + quads at frag 28 + b2|b3 (512 B)
#define OFF_Q (28*256)
#define OFF_B (29*256)
// launch_bounds(256,3): path-split keeps peak liveness within the 512/3=170
// budget (R6/R9/R11-R14: 3 blocks/CU, no spill).
__global__ __launch_bounds__(256, 3) void cnf_kernel(
    const float* __restrict__ tp, const float* __restrict__ x,
    const float* __restrict__ b4, float* __restrict__ out)
{
    __shared__ unsigned int ldsA[29*256 + 128]; // 30208 B

    // ---------- stage prepped frags + biases: vectorized global->LDS copy ----------
    {
        const u32x4* __restrict__ src = (const u32x4*)g_frags;
        u32x4* dst = (u32x4*)ldsA;
        for (int i = threadIdx.x; i < 29*64; i += 256) dst[i] = src[i];
        if (threadIdx.x < 32){
            ((u32x4*)(ldsA + OFF_B))[threadIdx.x] =
                ((const u32x4*)(g_frags + 53*256))[threadIdx.x];
        }
    }
    __syncthreads();

    const float4* w1q = (const float4*)&ldsA[OFF_Q];
    const float4* w4q = w1q + 32;
    const float*  b2l = (const float*)(ldsA + OFF_B);
    const float*  b3l = b2l + 64;
    const unsigned int* gW3 = g_frags + 29*256; // W3 bank stays in global (L1/L2-hot)

    // ---------- main (one 32-point group per wave; loop-free body, see ledger) ----------
    const int lane  = threadIdx.x & 63;
    const int g     = lane >> 5, l5 = lane & 31;
    const int lane4 = lane * 4;
    const int wid   = blockIdx.x * 4 + (threadIdx.x >> 6);

    const float ts  = tp[0];

    unsigned int tsh, tsm, tsl;
    split3s(ts, 1.0f, tsh, tsm, tsl);        // [ts, 1.0]; 1.0 exact

    const int n = wid*32 + l5;
    const float x0 = x[n*3 + 0], x1 = x[n*3 + 1];

    unsigned int xh, xm, xl;
    split3s(x0, x1, xh, xm, xl);
    const u32x4 Bp1 = { g ? xm : xh, g ? tsm : tsh, 0u, 0u };   // -> AhBh + AmBm
    const u32x4 Bp2 = { g ? xh : xm, g ? tsh : tsm, 0u, 0u };   // -> AhBm + AmBh
    const u32x4 Bp3 = { g ? xh : xl, g ? tsh : tsl, 0u, 0u };   // -> AhBl + AlBh

    u32x4 Bh[3][4], Bm0[4], Bl[4];          // SINGLE layer-interface buffer (80 regs)
    f32x2 dx0a = mk2(0.f), dx1a = mk2(0.f), tra = mk2(0.f);

    // ----- layer 1: z = W1ext @ [x0,x1,t,1] (6-term via 3 packed MFMAs) -----
    #pragma unroll
    for (int t = 0; t < 2; ++t){
        bf16x8 F1 = ldfrag(ldsA, 2*t,     lane4);   // [W1h | W1m]
        bf16x8 F3 = ldfrag(ldsA, 2*t + 1, lane4);   // [W1h | W1l]
        __builtin_amdgcn_s_setprio(1);
        f32x16 Ch = MFMA(F3, BC(Bp3), MFMA(F1, BC(Bp2), MFMA(F1, BC(Bp1), fzero())));
        __builtin_amdgcn_s_setprio(0);
        epilogue_L1(t, w1q, g, Ch, Bh, Bm0, Bl);
    }

    // ----- layer 2 (LDS frags) / layer 3 (global frags, fp32 L4 fused) -----
    hidden_layer<false>(ldsA, lane4, g, 4, 12, 20, b2l, nullptr, Bh, Bm0, Bl, dx0a, dx1a, tra);
    hidden_layer<true >(gW3,  lane4, g, 0,  8, 16, b3l, w4q,     Bh, Bm0, Bl, dx0a, dx1a, tra);

    // ----- pair-reduce + cross-half reduce -----
    float dx0 = dx0a.x + dx0a.y;
    float dx1 = dx1a.x + dx1a.y;
    float tr  = tra.x  + tra.y;
    dx0 += __shfl_xor(dx0, 32, 64);
    dx1 += __shfl_xor(dx1, 32, 64);
    tr  += __shfl_xor(tr,  32, 64);
    if (g == 0){
        const float b40 = b4[0], b41 = b4[1];   // loaded late: keeps them out of
        out[n*3 + 0] = dx0 + b40;               // the whole-kernel live range
        out[n*3 + 1] = dx1 + b41;
        out[n*3 + 2] = tr;
    }
}

extern "C" void kernel_launch(void* const* d_in, const int* in_sizes, int n_in,
                              void* d_out, int out_size, void* d_ws, size_t ws_size,
                              hipStream_t stream) {
    const float* t  = (const float*)d_in[0];
    const float* x  = (const float*)d_in[1];
    const float* W1 = (const float*)d_in[2];
    const float* b1 = (const float*)d_in[3];
    const float* W2 = (const float*)d_in[4];
    const float* b2 = (const float*)d_in[5];
    const float* W3 = (const float*)d_in[6];
    const float* b3 = (const float*)d_in[7];
    const float* W4 = (const float*)d_in[8];
    const float* b4 = (const float*)d_in[9];
    float* out = (float*)d_out;

    prep_kernel<<<22, 64, 0, stream>>>(W1, b1, W2, W3, W4, b2, b3);
    cnf_kernel<<<2048, 256, 0, stream>>>(t, x, b4, out);
}